// Round 7
// baseline (160.603 us; speedup 1.0000x reference)
//
#include <hip/hip_runtime.h>
#include <hip/hip_bf16.h>
#include <stdint.h>

#define DI __device__ __forceinline__

using f32x4 = __attribute__((ext_vector_type(4))) float;
using s16x8 = __attribute__((ext_vector_type(8))) short;

#define BB 64
#define SS 400
#define HH 512
#define VVOC 32000
#define MTOT (BB*SS)   // 25600

// ---------- helpers ----------
DI short bf16r(float f){
  __hip_bfloat16 h = __float2bfloat16(f);
  union { __hip_bfloat16 h; short s; } u; u.h = h; return u.s;
}
DI float sigm(float x){ return 1.f/(1.f + __expf(-x)); }
DI float tanhfast(float x){ x = fminf(x, 12.f); float e = __expf(2.f*x); return (e-1.f)/(e+1.f); }

DI void gload16b(const __hip_bfloat16* g, short* l){
  __builtin_amdgcn_global_load_lds(
      (const __attribute__((address_space(1))) __hip_bfloat16*)g,
      (__attribute__((address_space(3))) short*)l, 16, 0, 0);
}

DI float blkmax(float v, float* red, int t){
  #pragma unroll
  for (int o = 32; o; o >>= 1) v = fmaxf(v, __shfl_xor(v, o));
  if ((t & 63) == 0) red[t >> 6] = v;
  __syncthreads();
  v = fmaxf(fmaxf(red[0], red[1]), fmaxf(red[2], red[3]));
  __syncthreads();
  return v;
}
DI float blksum(float v, float* red, int t){
  #pragma unroll
  for (int o = 32; o; o >>= 1) v += __shfl_xor(v, o);
  if ((t & 63) == 0) red[t >> 6] = v;
  __syncthreads();
  v = red[0] + red[1] + red[2] + red[3];
  __syncthreads();
  return v;
}

DI s16x8 cvt8v(f32x4 a, f32x4 b){
  s16x8 o;
  o[0]=bf16r(a[0]); o[1]=bf16r(a[1]); o[2]=bf16r(a[2]); o[3]=bf16r(a[3]);
  o[4]=bf16r(b[0]); o[5]=bf16r(b[1]); o[6]=bf16r(b[2]); o[7]=bf16r(b[3]);
  return o;
}
DI s16x8 cvt8(const float* src){
  return cvt8v(((const f32x4*)src)[0], ((const f32x4*)src)[1]);
}

// bf16 LDS tile: row stride 64 shorts (128B), 8 chunks of 16B, slot = chunk ^ (row&7)
DI s16x8 fragload16(const short* tile, int rbase, int kk, int l){
  int r = rbase + (l & 15);
  int c = (kk >> 3) + (l >> 4);
  int slot = c ^ (r & 7);
  return *(const s16x8*)(tile + r*64 + slot*8);
}

// ---------- MFMA small GEMM body (shared): P[kseg] = A[64,K](kseg) @ W[N,K]^T(kseg) ----------
DI void mfma_small_body(const float* __restrict__ A, const float* __restrict__ W,
                        float* __restrict__ P, int K, int N, int c0, int kseg,
                        short* lsa, short* lsb, int t)
{
  const int kbeg = kseg*64;
  const int l = t & 63, w = t >> 6;
  #pragma unroll
  for (int q = 0; q < 2; ++q) {
    int it = q*256 + t;
    int r = it >> 3, c = it & 7;
    int slot = (c ^ (r & 7)) << 3;
    *(s16x8*)(lsa + r*64 + slot) = cvt8(A + (size_t)r*K + kbeg + c*8);
    *(s16x8*)(lsb + r*64 + slot) = cvt8(W + (size_t)(c0 + r)*K + kbeg + c*8);
  }
  __syncthreads();
  f32x4 acc[4];
  #pragma unroll
  for (int m = 0; m < 4; ++m) { f32x4 z = {0.f,0.f,0.f,0.f}; acc[m] = z; }
  #pragma unroll
  for (int kk = 0; kk < 64; kk += 32) {
    s16x8 bf = fragload16(lsb, w*16, kk, l);
    #pragma unroll
    for (int m = 0; m < 4; ++m) {
      s16x8 af = fragload16(lsa, m*16, kk, l);
      acc[m] = __builtin_amdgcn_mfma_f32_16x16x32_bf16(af, bf, acc[m], 0, 0, 0);
    }
  }
  const int kq = l >> 4, lc = l & 15;
  const int col = c0 + w*16 + lc;
  size_t pbase = (size_t)kseg * 64 * N;
  #pragma unroll
  for (int m = 0; m < 4; ++m)
    #pragma unroll
    for (int j = 0; j < 4; ++j)
      P[pbase + (size_t)(m*16 + kq*4 + j)*N + col] = acc[m][j];
}

// ---------- K1: enc/Wh cvt + mask detect + GRU gate partial GEMMs ----------
__global__ __launch_bounds__(256) void k_pre(
    const float* __restrict__ enc, const float* __restrict__ wh,
    short* __restrict__ enc16, short* __restrict__ wh16,
    const unsigned int* __restrict__ mask, int mwords, int* __restrict__ flags,
    const float* __restrict__ x, const float* __restrict__ hprev,
    const float* __restrict__ w_ih, const float* __restrict__ w_hh,
    float* __restrict__ GI, float* __restrict__ GH)
{
  __shared__ __align__(16) short ls[2][64*64];
  int b = blockIdx.x, t = threadIdx.x;
  if (b < 1600) {
    int i = b*256 + t;
    #pragma unroll
    for (int k = 0; k < 8; ++k) {
      int idx = i + k*409600;
      ((s16x8*)enc16)[idx] = cvt8(enc + (size_t)idx*8);
    }
  } else if (b < 1856) {
    int i = (b-1600)*256 + t;
    ((s16x8*)wh16)[i] = cvt8(wh + (size_t)i*8);
  } else if (b < 1864) {
    __shared__ int f;
    if (t == 0) f = 0;
    __syncthreads();
    int loc = 0;
    for (int i = (b-1856)*256 + t; i < mwords; i += 8*256) loc |= (mask[i] > 1u) ? 1 : 0;
    if (loc) atomicOr(&f, 1);
    __syncthreads();
    if (t == 0) flags[b-1856] = f;
  } else {
    int gb = b - 1864;              // 0..383
    int colI = gb % 24;
    int kseg = (gb / 24) % 8;
    int z    = gb / 192;
    mfma_small_body(z ? hprev : x, z ? w_hh : w_ih, z ? GH : GI,
                    512, 1536, colI*64, kseg, ls[0], ls[1], t);
  }
}

// ---------- fused GRU gate + q projection (one block per batch row) ----------
__global__ __launch_bounds__(256) void fused_hidq(
    const float* __restrict__ GI, const float* __restrict__ GH,
    const float* __restrict__ b_ih, const float* __restrict__ b_hh,
    const float* __restrict__ hprev, const float* __restrict__ Ws_w,
    const float* __restrict__ Ws_b, const float* __restrict__ Wh_b,
    float* __restrict__ hid, float* __restrict__ concat, float* __restrict__ Q)
{
  __shared__ float sh[512];
  int b = blockIdx.x, t = threadIdx.x;
  for (int h = t; h < 512; h += 256) {
    float ir=0, iz=0, inn=0, hr=0, hz=0, hn=0;
    #pragma unroll
    for (int s = 0; s < 8; ++s) {
      const float* gi = GI + (size_t)s*(64*1536) + b*1536;
      const float* gh = GH + (size_t)s*(64*1536) + b*1536;
      ir += gi[h];      iz += gi[512+h];  inn += gi[1024+h];
      hr += gh[h];      hz += gh[512+h];  hn  += gh[1024+h];
    }
    ir += b_ih[h]; iz += b_ih[512+h]; inn += b_ih[1024+h];
    hr += b_hh[h]; hz += b_hh[512+h]; hn  += b_hh[1024+h];
    float r = sigm(ir + hr), z = sigm(iz + hz);
    float n = tanhfast(inn + r*hn);
    float hv = (1.f - z)*n + z*hprev[b*512 + h];
    hid[b*512 + h] = hv;
    concat[b*1536 + h] = hv;
    sh[h] = hv;
  }
  __syncthreads();
  for (int c = t; c < 512; c += 256) {
    const f32x4* wrow = (const f32x4*)(Ws_w + (size_t)c*512);
    float a0=0.f, a1=0.f, a2=0.f, a3=0.f;
    #pragma unroll 8
    for (int k4 = 0; k4 < 128; ++k4) {
      f32x4 wv = wrow[k4];
      f32x4 hv = *(const f32x4*)(sh + k4*4);
      a0 += wv[0]*hv[0]; a1 += wv[1]*hv[1]; a2 += wv[2]*hv[2]; a3 += wv[3]*hv[3];
    }
    Q[b*512 + c] = (a0+a1)+(a2+a3) + Ws_b[c] + Wh_b[c];
  }
}

// ---------- bf16 score GEMM: 128 rows x 256 cols per block, 8 waves ----------
// B (Wh) re-reads stay in XCD-local L2 (1 MB total); A (enc) read ~once from L3.
__global__ __launch_bounds__(512) void score_gemm_bf16(
    const __hip_bfloat16* __restrict__ A, const __hip_bfloat16* __restrict__ Bw,
    const float* __restrict__ qv, const float* __restrict__ vb, float* __restrict__ dst)
{
  __shared__ __align__(16) short lsa[128*64];   // 16 KB
  __shared__ __align__(16) short lsb[256*64];   // 32 KB
  const int t = threadIdx.x;
  const int l = t & 63;
  const int w = t >> 6;           // 0..7
  const int wm = w >> 2;          // 0..1  (64-row half)
  const int wn = w & 3;           // 0..3  (64-col quarter)
  // 400 blocks; XCD-chunked swizzle, colb innermost so both colbs of an mrow share an XCD
  const int phys = blockIdx.x;
  const int logical = (phys & 7)*50 + (phys >> 3);
  const int mrow = (logical >> 1) * 128;
  const int colb = logical & 1;
  const int ncol = colb * 256;

  f32x4 acc[4][4];
  #pragma unroll
  for (int m = 0; m < 4; ++m)
    #pragma unroll
    for (int n = 0; n < 4; ++n) { f32x4 z = {0.f,0.f,0.f,0.f}; acc[m][n] = z; }

  for (int k0 = 0; k0 < 1024; k0 += 64) {
    #pragma unroll
    for (int i = 0; i < 2; ++i) {            // A tile: 1024 chunks of 16B
      int ci = i*512 + t;
      int r = ci >> 3, slot = ci & 7;
      int c = slot ^ (r & 7);                // pre-swizzled global src, lane-linear LDS dest
      gload16b(A + (size_t)(mrow + r)*1024 + k0 + c*8, lsa + ci*8);
    }
    #pragma unroll
    for (int i = 0; i < 4; ++i) {            // B tile: 2048 chunks
      int ci = i*512 + t;
      int r = ci >> 3, slot = ci & 7;
      int c = slot ^ (r & 7);
      gload16b(Bw + (size_t)(ncol + r)*1024 + k0 + c*8, lsb + ci*8);
    }
    __syncthreads();                          // compiler drains vmcnt before barrier
    #pragma unroll
    for (int kk = 0; kk < 64; kk += 32) {
      s16x8 bf[4];
      #pragma unroll
      for (int n = 0; n < 4; ++n) bf[n] = fragload16(lsb, wn*64 + n*16, kk, l);
      #pragma unroll
      for (int m = 0; m < 4; ++m) {
        s16x8 af = fragload16(lsa, wm*64 + m*16, kk, l);
        #pragma unroll
        for (int n = 0; n < 4; ++n)
          acc[m][n] = __builtin_amdgcn_mfma_f32_16x16x32_bf16(af, bf[n], acc[m][n], 0, 0, 0);
      }
    }
    __syncthreads();
  }

  const int kq = l >> 4, lc = l & 15;
  float vv[4];
  #pragma unroll
  for (int n = 0; n < 4; ++n) vv[n] = vb[ncol + wn*64 + n*16 + lc];
  const int seg = colb*4 + wn;               // 8 partial segments
  #pragma unroll
  for (int m = 0; m < 4; ++m) {
    #pragma unroll
    for (int j = 0; j < 4; ++j) {
      int r = mrow + wm*64 + m*16 + kq*4 + j;
      int b = r / SS;
      const float* qb = qv + b*HH + ncol + wn*64 + lc;
      float ps = 0.f;
      #pragma unroll
      for (int n = 0; n < 4; ++n) ps += vv[n]*tanhfast(acc[m][n][j] + qb[n*16]);
      #pragma unroll
      for (int o = 1; o < 16; o <<= 1) ps += __shfl_xor(ps, o);
      if (lc == 0) dst[seg*MTOT + r] = ps;
    }
  }
}

// ---------- vocab GEMM with register prefetch: logits = OUT @ Vhat^T + Vb ----------
__global__ __launch_bounds__(256) void vocab_gemm(
    const float* __restrict__ OUTm, const float* __restrict__ Vhat,
    const float* __restrict__ Vb, float* __restrict__ logits,
    float* __restrict__ MAXP, float* __restrict__ SUMP)
{
  __shared__ __align__(16) short lsa[64*64];
  __shared__ __align__(16) short lsb[64*64];
  __shared__ float red[64][8];
  const int t = threadIdx.x, l = t & 63, w = t >> 6;
  const int vrow0 = blockIdx.x * 64;

  f32x4 acc[4];
  #pragma unroll
  for (int m = 0; m < 4; ++m) { f32x4 z = {0.f,0.f,0.f,0.f}; acc[m] = z; }

  f32x4 pa0[2][2], pb0[2][2], pa1[2][2], pb1[2][2];

  #define VLOAD(pa, pb, k0)                                                     \
    _Pragma("unroll")                                                           \
    for (int q = 0; q < 2; ++q) {                                               \
      int it = q*256 + t; int r = it >> 3, c = it & 7;                          \
      const f32x4* ap = (const f32x4*)(OUTm + (size_t)r*512 + (k0) + c*8);      \
      pa[q][0] = ap[0]; pa[q][1] = ap[1];                                       \
      const f32x4* bp = (const f32x4*)(Vhat + (size_t)(vrow0 + r)*512 + (k0) + c*8); \
      pb[q][0] = bp[0]; pb[q][1] = bp[1];                                       \
    }
  #define VSTEP(pa, pb)                                                         \
    _Pragma("unroll")                                                           \
    for (int q = 0; q < 2; ++q) {                                               \
      int it = q*256 + t; int r = it >> 3, c = it & 7;                          \
      int slot = (c ^ (r & 7)) << 3;                                            \
      *(s16x8*)(lsa + r*64 + slot) = cvt8v(pa[q][0], pa[q][1]);                 \
      *(s16x8*)(lsb + r*64 + slot) = cvt8v(pb[q][0], pb[q][1]);                 \
    }                                                                           \
    __syncthreads();                                                            \
    _Pragma("unroll")                                                           \
    for (int kk = 0; kk < 64; kk += 32) {                                       \
      s16x8 bf = fragload16(lsb, w*16, kk, l);                                  \
      _Pragma("unroll")                                                         \
      for (int m = 0; m < 4; ++m) {                                             \
        s16x8 af = fragload16(lsa, m*16, kk, l);                                \
        acc[m] = __builtin_amdgcn_mfma_f32_16x16x32_bf16(af, bf, acc[m], 0,0,0);\
      }                                                                         \
    }                                                                           \
    __syncthreads();

  VLOAD(pa0, pb0, 0)
  #pragma unroll
  for (int s2 = 0; s2 < 4; ++s2) {
    int k0 = s2*128;
    if (k0 + 64 < 512) { VLOAD(pa1, pb1, k0 + 64) }
    VSTEP(pa0, pb0)
    if (k0 + 128 < 512) { VLOAD(pa0, pb0, k0 + 128) }
    VSTEP(pa1, pb1)
  }
  #undef VLOAD
  #undef VSTEP

  const int kq = l >> 4, lc = l & 15;
  const int voc = vrow0 + w*16 + lc;
  const float bias = Vb[voc];
  #pragma unroll
  for (int m = 0; m < 4; ++m)
    #pragma unroll
    for (int j = 0; j < 4; ++j) {
      acc[m][j] += bias;
      logits[(size_t)(m*16 + kq*4 + j)*VVOC + voc] = acc[m][j];
    }
  #pragma unroll
  for (int m = 0; m < 4; ++m)
    #pragma unroll
    for (int j = 0; j < 4; ++j) {
      float v = acc[m][j];
      #pragma unroll
      for (int o = 1; o < 16; o <<= 1) v = fmaxf(v, __shfl_xor(v, o));
      if (lc == 0) red[m*16 + kq*4 + j][w] = v;
    }
  __syncthreads();
  float gmax[4][4];
  #pragma unroll
  for (int m = 0; m < 4; ++m)
    #pragma unroll
    for (int j = 0; j < 4; ++j) {
      int row = m*16 + kq*4 + j;
      gmax[m][j] = fmaxf(fmaxf(red[row][0], red[row][1]), fmaxf(red[row][2], red[row][3]));
    }
  __syncthreads();
  #pragma unroll
  for (int m = 0; m < 4; ++m)
    #pragma unroll
    for (int j = 0; j < 4; ++j) {
      float s = __expf(acc[m][j] - gmax[m][j]);
      #pragma unroll
      for (int o = 1; o < 16; o <<= 1) s += __shfl_xor(s, o);
      if (lc == 0) red[m*16 + kq*4 + j][4 + w] = s;
    }
  __syncthreads();
  if (t < 64) {
    float M = fmaxf(fmaxf(red[t][0], red[t][1]), fmaxf(red[t][2], red[t][3]));
    float S = red[t][4] + red[t][5] + red[t][6] + red[t][7];
    MAXP[blockIdx.x*64 + t] = M;
    SUMP[blockIdx.x*64 + t] = S;
  }
}

// ---------- vocab softmax normalize ----------
__global__ __launch_bounds__(256) void vnorm(
    const float* __restrict__ MAXP, const float* __restrict__ SUMP,
    float* __restrict__ logits)
{
  __shared__ float red[4];
  int b = blockIdx.x, q = blockIdx.y, t = threadIdx.x;
  float m = -INFINITY;
  for (int i = t; i < 500; i += 256) m = fmaxf(m, MAXP[i*64 + b]);
  m = blkmax(m, red, t);
  float z = 0.f;
  for (int i = t; i < 500; i += 256) z += SUMP[i*64 + b] * __expf(MAXP[i*64 + b] - m);
  z = blksum(z, red, t);
  float inv = 1.f / z;
  f32x4* p = (f32x4*)(logits + (size_t)b*VVOC + q*8000);
  for (int i = t; i < 2000; i += 256) {
    f32x4 v = p[i];
    #pragma unroll
    for (int c = 0; c < 4; ++c) v[c] = __expf(v[c] - m) * inv;
    p[i] = v;
  }
}

// ---------- standalone small GEMM (out-projection) ----------
__global__ __launch_bounds__(256) void mfma_small(
    const float* __restrict__ A, const float* __restrict__ W,
    float* __restrict__ P, int K, int N)
{
  __shared__ __align__(16) short ls[2][64*64];
  mfma_small_body(A, W, P, K, N, blockIdx.x*64, blockIdx.y, ls[0], ls[1], threadIdx.x);
}

// ---------- combine K-split partials + biases ----------
__global__ void combineN(const float* __restrict__ P, const float* __restrict__ b1,
                         float* __restrict__ dstv, int N, int total, int nseg)
{
  int i = blockIdx.x*256 + threadIdx.x;
  if (i >= total) return;
  float a = 0.f;
  for (int s = 0; s < nseg; ++s) a += P[(size_t)s*total + i];
  if (b1) a += b1[i % N];
  dstv[i] = a;
}

// ---------- masked softmax over S ----------
__global__ void softmax_s(const float* __restrict__ part, const void* __restrict__ mask,
                          const int* __restrict__ flags, float* __restrict__ attn)
{
  __shared__ float red[4];
  int b = blockIdx.x, t = threadIdx.x;
  bool isbyte = (flags[0]|flags[1]|flags[2]|flags[3]|flags[4]|flags[5]|flags[6]|flags[7]) != 0;
  float sc0, sc1 = -INFINITY;
  {
    float v = 0.f;
    #pragma unroll
    for (int p = 0; p < 8; ++p) v += part[p*MTOT + b*SS + t];
    bool mv = isbyte ? (((const unsigned char*)mask)[b*SS + t] != 0)
                     : (((const int*)mask)[b*SS + t] != 0);
    sc0 = mv ? v : -INFINITY;
  }
  int s1 = t + 256;
  if (s1 < SS) {
    float v = 0.f;
    #pragma unroll
    for (int p = 0; p < 8; ++p) v += part[p*MTOT + b*SS + s1];
    bool mv = isbyte ? (((const unsigned char*)mask)[b*SS + s1] != 0)
                     : (((const int*)mask)[b*SS + s1] != 0);
    sc1 = mv ? v : -INFINITY;
  }
  float mx = blkmax(fmaxf(sc0, sc1), red, t);
  float e0 = __expf(sc0 - mx), e1 = __expf(sc1 - mx);
  float sum = blksum(e0 + e1, red, t);
  float inv = 1.f / sum;
  attn[b*SS + t] = e0 * inv;
  if (s1 < SS) attn[b*SS + s1] = e1 * inv;
}

// ---------- context partials: CTXP[sq][b][1024] over 8 S-slices of 50 ----------
__global__ void ctx_part(const float* __restrict__ attn, const unsigned int* __restrict__ enc16,
                         float* __restrict__ CTXP)
{
  int b = blockIdx.x, dh = blockIdx.y, sq = blockIdx.z;
  int d0 = dh*512 + threadIdx.x*2;
  const float* a = attn + b*SS + sq*50;
  const unsigned int* e = enc16 + (((size_t)(b*SS + sq*50)*1024 + d0) >> 1);
  float lo = 0.f, hi = 0.f;
  #pragma unroll 5
  for (int s = 0; s < 50; ++s) {
    unsigned int u = e[(size_t)s*512];
    float av = a[s];
    lo += av * __uint_as_float(u << 16);
    hi += av * __uint_as_float(u & 0xffff0000u);
  }
  float* dst = CTXP + (size_t)sq*65536 + b*1024 + d0;
  dst[0] = lo; dst[1] = hi;
}

// ---------- ctx combine: ctx (d_out) + CONCAT[:,512:] ----------
__global__ void ctx_combine(const float* __restrict__ CTXP, float* __restrict__ ctx,
                            float* __restrict__ concat)
{
  int b = blockIdx.x;
  for (int d = threadIdx.x; d < 1024; d += 256) {
    float s = 0.f;
    #pragma unroll
    for (int q = 0; q < 8; ++q) s += CTXP[q*65536 + b*1024 + d];
    ctx[b*1024 + d] = s;
    concat[b*1536 + 512 + d] = s;
  }
}

// ---------- launch ----------
extern "C" void kernel_launch(void* const* d_in, const int* in_sizes, int n_in,
                              void* d_out, int out_size, void* d_ws, size_t ws_size,
                              hipStream_t stream) {
  (void)in_sizes; (void)n_in; (void)out_size; (void)ws_size;
  const float* x      = (const float*)d_in[0];
  const float* hprev  = (const float*)d_in[1];
  const float* enc    = (const float*)d_in[2];
  const void*  mask   = d_in[3];
  const float* w_ih   = (const float*)d_in[4];
  const float* w_hh   = (const float*)d_in[5];
  const float* b_ih   = (const float*)d_in[6];
  const float* b_hh   = (const float*)d_in[7];
  const float* Wh_w   = (const float*)d_in[8];
  const float* Wh_b   = (const float*)d_in[9];
  const float* Ws_w   = (const float*)d_in[10];
  const float* Ws_b   = (const float*)d_in[11];
  const float* vatt   = (const float*)d_in[12];
  const float* V_w    = (const float*)d_in[13];
  const float* V_b    = (const float*)d_in[14];
  const float* Vhat_w = (const float*)d_in[15];
  const float* Vhat_b = (const float*)d_in[16];

  float* out   = (float*)d_out;
  float* vocab = out;                    // [64,32000]
  float* attn  = out + 2048000;          // [64,400]
  float* ctx   = out + 2073600;          // [64,1024]
  float* hid   = out + 2139136;          // [64,512]

  float* WS     = (float*)d_ws;
  int*   FLAGS  = (int*)d_ws;            // 16 ints
  float* GI     = WS + 16;               // 8*64*1536 = 786432
  float* GH     = GI + 786432;           // 786432
  float* Q      = GH + 786432;           // 32768
  float* OUT    = Q + 32768;             // 32768
  float* PART   = OUT + 32768;           // 8*25600 = 204800
  float* MAXP   = PART + 204800;         // 32000
  float* SUMP   = MAXP + 32000;          // 32000
  float* CTXP   = SUMP + 32000;          // 8*64*1024 = 524288
  float* OUTP   = CTXP + 524288;         // 24*64*512 = 786432
  float* CONCAT = OUTP + 786432;         // 64*1536 = 98304
  float* ENDF   = CONCAT + 98304;
  size_t f32_bytes = ((size_t)((char*)ENDF - (char*)d_ws) + 15) & ~(size_t)15;
  short* ENC16 = (short*)((char*)d_ws + f32_bytes);   // 25600*1024
  short* WH16  = ENC16 + (size_t)25600*1024;          // 512*1024

  // 1. cvt enc+Wh, mask detect, GRU gi/gh partial GEMMs — one kernel
  k_pre<<<dim3(2248), 256, 0, stream>>>(enc, Wh_w, ENC16, WH16,
                                        (const unsigned int*)mask, 6400, FLAGS,
                                        x, hprev, w_ih, w_hh, GI, GH);
  // 2. GRU gate + q projection fused
  fused_hidq<<<dim3(64), 256, 0, stream>>>(GI, GH, b_ih, b_hh, hprev,
                                           Ws_w, Ws_b, Wh_b, hid, CONCAT, Q);
  // 3. attention score GEMM (128x256 tiles, L2-resident B re-reads)
  score_gemm_bf16<<<dim3(400), 512, 0, stream>>>(
      (const __hip_bfloat16*)ENC16, (const __hip_bfloat16*)WH16, Q, vatt, PART);
  // 4. masked softmax over S
  softmax_s<<<dim3(64), 256, 0, stream>>>(PART, mask, FLAGS, attn);
  // 5-6. context partials + combine
  ctx_part<<<dim3(64, 2, 8), 256, 0, stream>>>(attn, (const unsigned int*)ENC16, CTXP);
  ctx_combine<<<dim3(64), 256, 0, stream>>>(CTXP, ctx, CONCAT);
  // 7-8. out = CONCAT@V_w^T + V_b (K-split 24)
  mfma_small<<<dim3(8, 24), 256, 0, stream>>>(CONCAT, V_w, OUTP, 1536, 512);
  combineN<<<dim3(128), 256, 0, stream>>>(OUTP, V_b, OUT, 512, 32768, 24);
  // 9. vocab GEMM + softmax partials
  vocab_gemm<<<dim3(500), 256, 0, stream>>>(OUT, Vhat_w, Vhat_b, vocab, MAXP, SUMP);
  // 10. softmax normalize
  vnorm<<<dim3(64, 4), 256, 0, stream>>>(MAXP, SUMP, vocab);
}

// Round 8
// 152.629 us; speedup vs baseline: 1.0522x; 1.0522x over previous
//
#include <hip/hip_runtime.h>
#include <hip/hip_bf16.h>
#include <stdint.h>

#define DI __device__ __forceinline__

using f32x2 = __attribute__((ext_vector_type(2))) float;
using f32x4 = __attribute__((ext_vector_type(4))) float;
using s16x8 = __attribute__((ext_vector_type(8))) short;

#define BB 64
#define SS 400
#define HH 512
#define VVOC 32000
#define MTOT (BB*SS)   // 25600

// ---------- helpers ----------
DI short bf16r(float f){
  __hip_bfloat16 h = __float2bfloat16(f);
  union { __hip_bfloat16 h; short s; } u; u.h = h; return u.s;
}
DI float sigm(float x){ return 1.f/(1.f + __expf(-x)); }
DI float tanhfast(float x){ x = fminf(x, 12.f); float e = __expf(2.f*x); return (e-1.f)/(e+1.f); }

DI void gload16b(const __hip_bfloat16* g, short* l){
  __builtin_amdgcn_global_load_lds(
      (const __attribute__((address_space(1))) __hip_bfloat16*)g,
      (__attribute__((address_space(3))) short*)l, 16, 0, 0);
}

DI float blkmax(float v, float* red, int t){
  #pragma unroll
  for (int o = 32; o; o >>= 1) v = fmaxf(v, __shfl_xor(v, o));
  if ((t & 63) == 0) red[t >> 6] = v;
  __syncthreads();
  v = fmaxf(fmaxf(red[0], red[1]), fmaxf(red[2], red[3]));
  __syncthreads();
  return v;
}
DI float blksum(float v, float* red, int t){
  #pragma unroll
  for (int o = 32; o; o >>= 1) v += __shfl_xor(v, o);
  if ((t & 63) == 0) red[t >> 6] = v;
  __syncthreads();
  v = red[0] + red[1] + red[2] + red[3];
  __syncthreads();
  return v;
}

DI s16x8 cvt8v(f32x4 a, f32x4 b){
  s16x8 o;
  o[0]=bf16r(a[0]); o[1]=bf16r(a[1]); o[2]=bf16r(a[2]); o[3]=bf16r(a[3]);
  o[4]=bf16r(b[0]); o[5]=bf16r(b[1]); o[6]=bf16r(b[2]); o[7]=bf16r(b[3]);
  return o;
}
DI s16x8 cvt8(const float* src){
  return cvt8v(((const f32x4*)src)[0], ((const f32x4*)src)[1]);
}

// bf16 LDS tile: row stride 64 shorts (128B), 8 chunks of 16B, slot = chunk ^ (row&7)
DI s16x8 fragload16(const short* tile, int rbase, int kk, int l){
  int r = rbase + (l & 15);
  int c = (kk >> 3) + (l >> 4);
  int slot = c ^ (r & 7);
  return *(const s16x8*)(tile + r*64 + slot*8);
}

// ---------- MFMA small GEMM body: P[kseg] = A[64,K](kseg) @ W[N,K]^T(kseg) ----------
DI void mfma_small_body(const float* __restrict__ A, const float* __restrict__ W,
                        float* __restrict__ P, int K, int N, int c0, int kseg,
                        short* lsa, short* lsb, int t)
{
  const int kbeg = kseg*64;
  const int l = t & 63, w = t >> 6;
  #pragma unroll
  for (int q = 0; q < 2; ++q) {
    int it = q*256 + t;
    int r = it >> 3, c = it & 7;
    int slot = (c ^ (r & 7)) << 3;
    *(s16x8*)(lsa + r*64 + slot) = cvt8(A + (size_t)r*K + kbeg + c*8);
    *(s16x8*)(lsb + r*64 + slot) = cvt8(W + (size_t)(c0 + r)*K + kbeg + c*8);
  }
  __syncthreads();
  f32x4 acc[4];
  #pragma unroll
  for (int m = 0; m < 4; ++m) { f32x4 z = {0.f,0.f,0.f,0.f}; acc[m] = z; }
  #pragma unroll
  for (int kk = 0; kk < 64; kk += 32) {
    s16x8 bf = fragload16(lsb, w*16, kk, l);
    #pragma unroll
    for (int m = 0; m < 4; ++m) {
      s16x8 af = fragload16(lsa, m*16, kk, l);
      acc[m] = __builtin_amdgcn_mfma_f32_16x16x32_bf16(af, bf, acc[m], 0, 0, 0);
    }
  }
  const int kq = l >> 4, lc = l & 15;
  const int col = c0 + w*16 + lc;
  size_t pbase = (size_t)kseg * 64 * N;
  #pragma unroll
  for (int m = 0; m < 4; ++m)
    #pragma unroll
    for (int j = 0; j < 4; ++j)
      P[pbase + (size_t)(m*16 + kq*4 + j)*N + col] = acc[m][j];
}

// ---------- K1: Wh cvt + mask detect + GRU gate partial GEMMs ----------
__global__ __launch_bounds__(256) void k_pre(
    const float* __restrict__ wh, short* __restrict__ wh16,
    const unsigned int* __restrict__ mask, int mwords, int* __restrict__ flags,
    const float* __restrict__ x, const float* __restrict__ hprev,
    const float* __restrict__ w_ih, const float* __restrict__ w_hh,
    float* __restrict__ GI, float* __restrict__ GH)
{
  __shared__ __align__(16) short ls[2][64*64];
  int b = blockIdx.x, t = threadIdx.x;
  if (b < 256) {
    int i = b*256 + t;   // 65536 groups of 8
    ((s16x8*)wh16)[i] = cvt8(wh + (size_t)i*8);
  } else if (b < 264) {
    __shared__ int f;
    if (t == 0) f = 0;
    __syncthreads();
    int loc = 0;
    for (int i = (b-256)*256 + t; i < mwords; i += 8*256) loc |= (mask[i] > 1u) ? 1 : 0;
    if (loc) atomicOr(&f, 1);
    __syncthreads();
    if (t == 0) flags[b-256] = f;
  } else {
    int gb = b - 264;              // 0..383
    int colI = gb % 24;
    int kseg = (gb / 24) % 8;
    int z    = gb / 192;
    mfma_small_body(z ? hprev : x, z ? w_hh : w_ih, z ? GH : GI,
                    512, 1536, colI*64, kseg, ls[0], ls[1], t);
  }
}

// ---------- GRU gate combine ----------
__global__ void gru_gate(const float* __restrict__ GI, const float* __restrict__ GH,
                         const float* __restrict__ b_ih, const float* __restrict__ b_hh,
                         const float* __restrict__ hprev, float* __restrict__ hid,
                         float* __restrict__ concat)
{
  int i = blockIdx.x*256 + threadIdx.x;
  int b = i >> 9, h = i & 511;
  float ir=0, iz=0, inn=0, hr=0, hz=0, hn=0;
  #pragma unroll
  for (int s = 0; s < 8; ++s) {
    const float* gi = GI + (size_t)s*(64*1536) + b*1536;
    const float* gh = GH + (size_t)s*(64*1536) + b*1536;
    ir += gi[h];      iz += gi[512+h];  inn += gi[1024+h];
    hr += gh[h];      hz += gh[512+h];  hn  += gh[1024+h];
  }
  ir += b_ih[h]; iz += b_ih[512+h]; inn += b_ih[1024+h];
  hr += b_hh[h]; hz += b_hh[512+h]; hn  += b_hh[1024+h];
  float r = sigm(ir + hr), z = sigm(iz + hz);
  float n = tanhfast(inn + r*hn);
  float hv = (1.f - z)*n + z*hprev[i];
  hid[i] = hv;
  concat[b*1536 + h] = hv;
}

// ---------- standalone small GEMM ----------
__global__ __launch_bounds__(256) void mfma_small(
    const float* __restrict__ A, const float* __restrict__ W,
    float* __restrict__ P, int K, int N)
{
  __shared__ __align__(16) short ls[2][64*64];
  mfma_small_body(A, W, P, K, N, blockIdx.x*64, blockIdx.y, ls[0], ls[1], threadIdx.x);
}

// ---------- combine K-split partials + up to two biases ----------
__global__ void combineN(const float* __restrict__ P, const float* __restrict__ b1,
                         const float* __restrict__ b2, float* __restrict__ dstv,
                         int N, int total, int nseg)
{
  int i = blockIdx.x*256 + threadIdx.x;
  if (i >= total) return;
  float a = 0.f;
  for (int s = 0; s < nseg; ++s) a += P[(size_t)s*total + i];
  int c = i % N;
  if (b1) a += b1[c];
  if (b2) a += b2[c];
  dstv[i] = a;
}

// ---------- score GEMM: A f32 reg-staged, B bf16 gload_lds, 1 barrier/K-step ----------
// BM=64, BN=128, BK=64; 4 waves; wave tile 32x64 (2x4 rep of 16x16x32).
__global__ __launch_bounds__(256) void score_gemm_bf16(
    const float* __restrict__ A, const __hip_bfloat16* __restrict__ Bw,
    const float* __restrict__ qv, const float* __restrict__ vb, float* __restrict__ dst)
{
  __shared__ __align__(16) short lsa[2][64*64];    // 2 x 8 KB
  __shared__ __align__(16) short lsb[2][128*64];   // 2 x 16 KB
  const int t = threadIdx.x;
  const int l = t & 63;
  const int w = t >> 6;
  const int wm = w >> 1;          // 0..1 : 32-row half
  const int wn = w & 1;           // 0..1 : 64-col half
  // 1600 blocks; XCD-chunked: 4 colbs of one mrow stay on one XCD (A L2-reuse)
  const int phys = blockIdx.x;
  const int logical = (phys & 7)*200 + (phys >> 3);
  const int mrow = (logical >> 2) * 64;
  const int colb = logical & 3;
  const int ncol = colb * 128;

  // A staging geometry: thread t owns row ar = t>>2, 16 consecutive f32 at col aq*16
  const int ar = t >> 2;
  const int aq = t & 3;
  const float* abase = A + (size_t)(mrow + ar)*1024 + aq*16;
  const int as0 = ((2*aq    ) ^ (ar & 7)) << 3;    // swizzled LDS chunk slots
  const int as1 = ((2*aq + 1) ^ (ar & 7)) << 3;

  f32x4 acc[2][4];
  #pragma unroll
  for (int m = 0; m < 2; ++m)
    #pragma unroll
    for (int n = 0; n < 4; ++n) { f32x4 z = {0.f,0.f,0.f,0.f}; acc[m][n] = z; }

  f32x4 pa0, pa1, pa2, pa3;
  #define A_LOAD(k0) { const f32x4* ap = (const f32x4*)(abase + (k0));            \
                       pa0 = ap[0]; pa1 = ap[1]; pa2 = ap[2]; pa3 = ap[3]; }
  #define A_WRITE(buf) { *(s16x8*)(&lsa[buf][ar*64] + as0) = cvt8v(pa0, pa1);     \
                         *(s16x8*)(&lsa[buf][ar*64] + as1) = cvt8v(pa2, pa3); }
  #define B_STAGE(buf, k0)                                                        \
    _Pragma("unroll")                                                              \
    for (int i = 0; i < 4; ++i) {                                                  \
      int ci = i*256 + t;                                                          \
      int r = ci >> 3, slot = ci & 7;                                              \
      int c = slot ^ (r & 7);                                                      \
      gload16b(Bw + (size_t)(ncol + r)*1024 + (k0) + c*8, &lsb[buf][ci*8]);        \
    }

  // prologue
  A_LOAD(0)
  B_STAGE(0, 0)
  A_WRITE(0)
  __syncthreads();

  int cur = 0;
  for (int k = 0; k < 16; ++k) {
    if (k < 15) {
      A_LOAD((k+1)*64)          // issue early: f32 loads in flight during MFMA
      B_STAGE(cur ^ 1, (k+1)*64)
    }
    #pragma unroll
    for (int kk = 0; kk < 64; kk += 32) {
      s16x8 bf[4];
      #pragma unroll
      for (int n = 0; n < 4; ++n) bf[n] = fragload16(lsb[cur], wn*64 + n*16, kk, l);
      #pragma unroll
      for (int m = 0; m < 2; ++m) {
        s16x8 af = fragload16(lsa[cur], wm*32 + m*16, kk, l);
        #pragma unroll
        for (int n = 0; n < 4; ++n)
          acc[m][n] = __builtin_amdgcn_mfma_f32_16x16x32_bf16(af, bf[n], acc[m][n], 0, 0, 0);
      }
    }
    if (k < 15) A_WRITE(cur ^ 1)   // write-late into the other buffer
    __syncthreads();                // single barrier per step
    cur ^= 1;
  }
  #undef A_LOAD
  #undef A_WRITE
  #undef B_STAGE

  const int kq = l >> 4, lc = l & 15;
  float vv[4];
  #pragma unroll
  for (int n = 0; n < 4; ++n) vv[n] = vb[ncol + wn*64 + n*16 + lc];
  const int seg = colb*2 + wn;     // 8 partial segments
  #pragma unroll
  for (int m = 0; m < 2; ++m) {
    #pragma unroll
    for (int j = 0; j < 4; ++j) {
      int r = mrow + wm*32 + m*16 + kq*4 + j;
      int b = r / SS;
      const float* qb = qv + b*HH + ncol + wn*64 + lc;
      float ps = 0.f;
      #pragma unroll
      for (int n = 0; n < 4; ++n) ps += vv[n]*tanhfast(acc[m][n][j] + qb[n*16]);
      #pragma unroll
      for (int o = 1; o < 16; o <<= 1) ps += __shfl_xor(ps, o);
      if (lc == 0) dst[seg*MTOT + r] = ps;
    }
  }
}

// ---------- vocab GEMM with register prefetch ----------
__global__ __launch_bounds__(256) void vocab_gemm(
    const float* __restrict__ OUTm, const float* __restrict__ Vhat,
    const float* __restrict__ Vb, float* __restrict__ logits,
    float* __restrict__ MAXP, float* __restrict__ SUMP)
{
  __shared__ __align__(16) short lsa[64*64];
  __shared__ __align__(16) short lsb[64*64];
  __shared__ float red[64][8];
  const int t = threadIdx.x, l = t & 63, w = t >> 6;
  const int vrow0 = blockIdx.x * 64;

  f32x4 acc[4];
  #pragma unroll
  for (int m = 0; m < 4; ++m) { f32x4 z = {0.f,0.f,0.f,0.f}; acc[m] = z; }

  f32x4 pa0[2][2], pb0[2][2], pa1[2][2], pb1[2][2];

  #define VLOAD(pa, pb, k0)                                                     \
    _Pragma("unroll")                                                           \
    for (int q = 0; q < 2; ++q) {                                               \
      int it = q*256 + t; int r = it >> 3, c = it & 7;                          \
      const f32x4* ap = (const f32x4*)(OUTm + (size_t)r*512 + (k0) + c*8);      \
      pa[q][0] = ap[0]; pa[q][1] = ap[1];                                       \
      const f32x4* bp = (const f32x4*)(Vhat + (size_t)(vrow0 + r)*512 + (k0) + c*8); \
      pb[q][0] = bp[0]; pb[q][1] = bp[1];                                       \
    }
  #define VSTEP(pa, pb)                                                         \
    _Pragma("unroll")                                                           \
    for (int q = 0; q < 2; ++q) {                                               \
      int it = q*256 + t; int r = it >> 3, c = it & 7;                          \
      int slot = (c ^ (r & 7)) << 3;                                            \
      *(s16x8*)(lsa + r*64 + slot) = cvt8v(pa[q][0], pa[q][1]);                 \
      *(s16x8*)(lsb + r*64 + slot) = cvt8v(pb[q][0], pb[q][1]);                 \
    }                                                                           \
    __syncthreads();                                                            \
    _Pragma("unroll")                                                           \
    for (int kk = 0; kk < 64; kk += 32) {                                       \
      s16x8 bf = fragload16(lsb, w*16, kk, l);                                  \
      _Pragma("unroll")                                                         \
      for (int m = 0; m < 4; ++m) {                                             \
        s16x8 af = fragload16(lsa, m*16, kk, l);                                \
        acc[m] = __builtin_amdgcn_mfma_f32_16x16x32_bf16(af, bf, acc[m], 0,0,0);\
      }                                                                         \
    }                                                                           \
    __syncthreads();

  VLOAD(pa0, pb0, 0)
  #pragma unroll
  for (int s2 = 0; s2 < 4; ++s2) {
    int k0 = s2*128;
    if (k0 + 64 < 512) { VLOAD(pa1, pb1, k0 + 64) }
    VSTEP(pa0, pb0)
    if (k0 + 128 < 512) { VLOAD(pa0, pb0, k0 + 128) }
    VSTEP(pa1, pb1)
  }
  #undef VLOAD
  #undef VSTEP

  const int kq = l >> 4, lc = l & 15;
  const int voc = vrow0 + w*16 + lc;
  const float bias = Vb[voc];
  #pragma unroll
  for (int m = 0; m < 4; ++m)
    #pragma unroll
    for (int j = 0; j < 4; ++j) {
      acc[m][j] += bias;
      logits[(size_t)(m*16 + kq*4 + j)*VVOC + voc] = acc[m][j];
    }
  #pragma unroll
  for (int m = 0; m < 4; ++m)
    #pragma unroll
    for (int j = 0; j < 4; ++j) {
      float v = acc[m][j];
      #pragma unroll
      for (int o = 1; o < 16; o <<= 1) v = fmaxf(v, __shfl_xor(v, o));
      if (lc == 0) red[m*16 + kq*4 + j][w] = v;
    }
  __syncthreads();
  float gmax[4][4];
  #pragma unroll
  for (int m = 0; m < 4; ++m)
    #pragma unroll
    for (int j = 0; j < 4; ++j) {
      int row = m*16 + kq*4 + j;
      gmax[m][j] = fmaxf(fmaxf(red[row][0], red[row][1]), fmaxf(red[row][2], red[row][3]));
    }
  __syncthreads();
  #pragma unroll
  for (int m = 0; m < 4; ++m)
    #pragma unroll
    for (int j = 0; j < 4; ++j) {
      float s = __expf(acc[m][j] - gmax[m][j]);
      #pragma unroll
      for (int o = 1; o < 16; o <<= 1) s += __shfl_xor(s, o);
      if (lc == 0) red[m*16 + kq*4 + j][4 + w] = s;
    }
  __syncthreads();
  if (t < 64) {
    float M = fmaxf(fmaxf(red[t][0], red[t][1]), fmaxf(red[t][2], red[t][3]));
    float S = red[t][4] + red[t][5] + red[t][6] + red[t][7];
    MAXP[blockIdx.x*64 + t] = M;
    SUMP[blockIdx.x*64 + t] = S;
  }
}

// ---------- vocab softmax normalize ----------
__global__ __launch_bounds__(256) void vnorm(
    const float* __restrict__ MAXP, const float* __restrict__ SUMP,
    float* __restrict__ logits)
{
  __shared__ float red[4];
  int b = blockIdx.x, q = blockIdx.y, t = threadIdx.x;
  float m = -INFINITY;
  for (int i = t; i < 500; i += 256) m = fmaxf(m, MAXP[i*64 + b]);
  m = blkmax(m, red, t);
  float z = 0.f;
  for (int i = t; i < 500; i += 256) z += SUMP[i*64 + b] * __expf(MAXP[i*64 + b] - m);
  z = blksum(z, red, t);
  float inv = 1.f / z;
  f32x4* p = (f32x4*)(logits + (size_t)b*VVOC + q*8000);
  for (int i = t; i < 2000; i += 256) {
    f32x4 v = p[i];
    #pragma unroll
    for (int c = 0; c < 4; ++c) v[c] = __expf(v[c] - m) * inv;
    p[i] = v;
  }
}

// ---------- masked softmax over S ----------
__global__ void softmax_s(const float* __restrict__ part, const void* __restrict__ mask,
                          const int* __restrict__ flags, float* __restrict__ attn)
{
  __shared__ float red[4];
  int b = blockIdx.x, t = threadIdx.x;
  bool isbyte = (flags[0]|flags[1]|flags[2]|flags[3]|flags[4]|flags[5]|flags[6]|flags[7]) != 0;
  float sc0, sc1 = -INFINITY;
  {
    float v = 0.f;
    #pragma unroll
    for (int p = 0; p < 8; ++p) v += part[p*MTOT + b*SS + t];
    bool mv = isbyte ? (((const unsigned char*)mask)[b*SS + t] != 0)
                     : (((const int*)mask)[b*SS + t] != 0);
    sc0 = mv ? v : -INFINITY;
  }
  int s1 = t + 256;
  if (s1 < SS) {
    float v = 0.f;
    #pragma unroll
    for (int p = 0; p < 8; ++p) v += part[p*MTOT + b*SS + s1];
    bool mv = isbyte ? (((const unsigned char*)mask)[b*SS + s1] != 0)
                     : (((const int*)mask)[b*SS + s1] != 0);
    sc1 = mv ? v : -INFINITY;
  }
  float mx = blkmax(fmaxf(sc0, sc1), red, t);
  float e0 = __expf(sc0 - mx), e1 = __expf(sc1 - mx);
  float sum = blksum(e0 + e1, red, t);
  float inv = 1.f / sum;
  attn[b*SS + t] = e0 * inv;
  if (s1 < SS) attn[b*SS + s1] = e1 * inv;
}

// ---------- context partials from f32 enc: CTXP[sq][b][1024], 8 S-slices of 50 ----------
__global__ void ctx_part(const float* __restrict__ attn, const float* __restrict__ enc,
                         float* __restrict__ CTXP)
{
  int b = blockIdx.x, dh = blockIdx.y, sq = blockIdx.z;
  int d0 = dh*512 + threadIdx.x*2;
  const float* a = attn + b*SS + sq*50;
  const float* e = enc + (size_t)(b*SS + sq*50)*1024 + d0;
  float lo = 0.f, hi = 0.f;
  #pragma unroll 5
  for (int s = 0; s < 50; ++s) {
    f32x2 u = *(const f32x2*)(e + (size_t)s*1024);
    float av = a[s];
    lo += av * u[0];
    hi += av * u[1];
  }
  float* dst = CTXP + (size_t)sq*65536 + b*1024 + d0;
  dst[0] = lo; dst[1] = hi;
}

// ---------- ctx combine: ctx (d_out) + CONCAT[:,512:] ----------
__global__ void ctx_combine(const float* __restrict__ CTXP, float* __restrict__ ctx,
                            float* __restrict__ concat)
{
  int b = blockIdx.x;
  for (int d = threadIdx.x; d < 1024; d += 256) {
    float s = 0.f;
    #pragma unroll
    for (int q = 0; q < 8; ++q) s += CTXP[q*65536 + b*1024 + d];
    ctx[b*1024 + d] = s;
    concat[b*1536 + 512 + d] = s;
  }
}

// ---------- launch ----------
extern "C" void kernel_launch(void* const* d_in, const int* in_sizes, int n_in,
                              void* d_out, int out_size, void* d_ws, size_t ws_size,
                              hipStream_t stream) {
  (void)in_sizes; (void)n_in; (void)out_size; (void)ws_size;
  const float* x      = (const float*)d_in[0];
  const float* hprev  = (const float*)d_in[1];
  const float* enc    = (const float*)d_in[2];
  const void*  mask   = d_in[3];
  const float* w_ih   = (const float*)d_in[4];
  const float* w_hh   = (const float*)d_in[5];
  const float* b_ih   = (const float*)d_in[6];
  const float* b_hh   = (const float*)d_in[7];
  const float* Wh_w   = (const float*)d_in[8];
  const float* Wh_b   = (const float*)d_in[9];
  const float* Ws_w   = (const float*)d_in[10];
  const float* Ws_b   = (const float*)d_in[11];
  const float* vatt   = (const float*)d_in[12];
  const float* V_w    = (const float*)d_in[13];
  const float* V_b    = (const float*)d_in[14];
  const float* Vhat_w = (const float*)d_in[15];
  const float* Vhat_b = (const float*)d_in[16];

  float* out   = (float*)d_out;
  float* vocab = out;                    // [64,32000]
  float* attn  = out + 2048000;          // [64,400]
  float* ctx   = out + 2073600;          // [64,1024]
  float* hid   = out + 2139136;          // [64,512]

  float* WS     = (float*)d_ws;
  int*   FLAGS  = (int*)d_ws;            // 16 ints
  float* GI     = WS + 16;               // 8*64*1536 = 786432
  float* GH     = GI + 786432;           // 786432
  float* QP     = GH + 786432;           // 8*64*512 = 262144
  float* Q      = QP + 262144;           // 32768
  float* OUT    = Q + 32768;             // 32768
  float* PART   = OUT + 32768;           // 8*25600 = 204800
  float* MAXP   = PART + 204800;         // 32000
  float* SUMP   = MAXP + 32000;          // 32000
  float* CTXP   = SUMP + 32000;          // 8*64*1024 = 524288
  float* OUTP   = CTXP + 524288;         // 24*64*512 = 786432
  float* CONCAT = OUTP + 786432;         // 64*1536 = 98304
  float* ENDF   = CONCAT + 98304;
  size_t f32_bytes = ((size_t)((char*)ENDF - (char*)d_ws) + 15) & ~(size_t)15;
  short* WH16  = (short*)((char*)d_ws + f32_bytes);   // 512*1024 bf16

  // 1. Wh cvt + mask detect + GRU gi/gh partials
  k_pre<<<dim3(648), 256, 0, stream>>>(Wh_w, WH16, (const unsigned int*)mask, 6400, FLAGS,
                                       x, hprev, w_ih, w_hh, GI, GH);
  // 2. GRU gate combine
  gru_gate<<<dim3(128), 256, 0, stream>>>(GI, GH, b_ih, b_hh, hprev, hid, CONCAT);
  // 3-4. q = hid@Ws^T + Ws_b + Wh_b
  mfma_small<<<dim3(8, 8), 256, 0, stream>>>(hid, Ws_w, QP, 512, 512);
  combineN<<<dim3(128), 256, 0, stream>>>(QP, Ws_b, Wh_b, Q, 512, 32768, 8);
  // 5. attention score GEMM (f32 A reg-staged, 1600 blocks, 1 barrier/step)
  score_gemm_bf16<<<dim3(1600), 256, 0, stream>>>(
      enc, (const __hip_bfloat16*)WH16, Q, vatt, PART);
  // 6. masked softmax over S
  softmax_s<<<dim3(64), 256, 0, stream>>>(PART, mask, FLAGS, attn);
  // 7-8. context partials (f32 enc) + combine
  ctx_part<<<dim3(64, 2, 8), 256, 0, stream>>>(attn, enc, CTXP);
  ctx_combine<<<dim3(64), 256, 0, stream>>>(CTXP, ctx, CONCAT);
  // 9-10. out = CONCAT@V_w^T + V_b (K-split 24)
  mfma_small<<<dim3(8, 24), 256, 0, stream>>>(CONCAT, V_w, OUTP, 1536, 512);
  combineN<<<dim3(128), 256, 0, stream>>>(OUTP, V_b, nullptr, OUT, 512, 32768, 24);
  // 11. vocab GEMM + softmax partials
  vocab_gemm<<<dim3(500), 256, 0, stream>>>(OUT, Vhat_w, Vhat_b, vocab, MAXP, SUMP);
  // 12. softmax normalize
  vnorm<<<dim3(64, 4), 256, 0, stream>>>(MAXP, SUMP, vocab);
}

// Round 9
// 134.225 us; speedup vs baseline: 1.1965x; 1.1371x over previous
//
#include <hip/hip_runtime.h>
#include <hip/hip_bf16.h>
#include <stdint.h>

#define DI __device__ __forceinline__

using f32x2 = __attribute__((ext_vector_type(2))) float;
using f32x4 = __attribute__((ext_vector_type(4))) float;
using s16x8 = __attribute__((ext_vector_type(8))) short;

#define BB 64
#define SS 400
#define HH 512
#define VVOC 32000
#define MTOT (BB*SS)   // 25600

// ---------- helpers ----------
DI short bf16r(float f){
  __hip_bfloat16 h = __float2bfloat16(f);
  union { __hip_bfloat16 h; short s; } u; u.h = h; return u.s;
}
DI float sigm(float x){ return 1.f/(1.f + __expf(-x)); }
DI float tanhfast(float x){ x = fminf(x, 12.f); float e = __expf(2.f*x); return (e-1.f)/(e+1.f); }

DI void gload16b(const __hip_bfloat16* g, short* l){
  __builtin_amdgcn_global_load_lds(
      (const __attribute__((address_space(1))) __hip_bfloat16*)g,
      (__attribute__((address_space(3))) short*)l, 16, 0, 0);
}

DI float blkmax(float v, float* red, int t){
  #pragma unroll
  for (int o = 32; o; o >>= 1) v = fmaxf(v, __shfl_xor(v, o));
  if ((t & 63) == 0) red[t >> 6] = v;
  __syncthreads();
  v = fmaxf(fmaxf(red[0], red[1]), fmaxf(red[2], red[3]));
  __syncthreads();
  return v;
}
DI float blksum(float v, float* red, int t){
  #pragma unroll
  for (int o = 32; o; o >>= 1) v += __shfl_xor(v, o);
  if ((t & 63) == 0) red[t >> 6] = v;
  __syncthreads();
  v = red[0] + red[1] + red[2] + red[3];
  __syncthreads();
  return v;
}

DI s16x8 cvt8v(f32x4 a, f32x4 b){
  s16x8 o;
  o[0]=bf16r(a[0]); o[1]=bf16r(a[1]); o[2]=bf16r(a[2]); o[3]=bf16r(a[3]);
  o[4]=bf16r(b[0]); o[5]=bf16r(b[1]); o[6]=bf16r(b[2]); o[7]=bf16r(b[3]);
  return o;
}
DI s16x8 cvt8(const float* src){
  return cvt8v(((const f32x4*)src)[0], ((const f32x4*)src)[1]);
}

// bf16 LDS tile: row stride 64 shorts (128B), 8 chunks of 16B, slot = chunk ^ (row&7)
DI s16x8 fragload16(const short* tile, int rbase, int kk, int l){
  int r = rbase + (l & 15);
  int c = (kk >> 3) + (l >> 4);
  int slot = c ^ (r & 7);
  return *(const s16x8*)(tile + r*64 + slot*8);
}

// ---------- MFMA small GEMM body: P[kseg] = A[64,K](kseg) @ W[N,K]^T(kseg) ----------
DI void mfma_small_body(const float* __restrict__ A, const float* __restrict__ W,
                        float* __restrict__ P, int K, int N, int c0, int kseg,
                        short* lsa, short* lsb, int t)
{
  const int kbeg = kseg*64;
  const int l = t & 63, w = t >> 6;
  #pragma unroll
  for (int q = 0; q < 2; ++q) {
    int it = q*256 + t;
    int r = it >> 3, c = it & 7;
    int slot = (c ^ (r & 7)) << 3;
    *(s16x8*)(lsa + r*64 + slot) = cvt8(A + (size_t)r*K + kbeg + c*8);
    *(s16x8*)(lsb + r*64 + slot) = cvt8(W + (size_t)(c0 + r)*K + kbeg + c*8);
  }
  __syncthreads();
  f32x4 acc[4];
  #pragma unroll
  for (int m = 0; m < 4; ++m) { f32x4 z = {0.f,0.f,0.f,0.f}; acc[m] = z; }
  #pragma unroll
  for (int kk = 0; kk < 64; kk += 32) {
    s16x8 bf = fragload16(lsb, w*16, kk, l);
    #pragma unroll
    for (int m = 0; m < 4; ++m) {
      s16x8 af = fragload16(lsa, m*16, kk, l);
      acc[m] = __builtin_amdgcn_mfma_f32_16x16x32_bf16(af, bf, acc[m], 0, 0, 0);
    }
  }
  const int kq = l >> 4, lc = l & 15;
  const int col = c0 + w*16 + lc;
  size_t pbase = (size_t)kseg * 64 * N;
  #pragma unroll
  for (int m = 0; m < 4; ++m)
    #pragma unroll
    for (int j = 0; j < 4; ++j)
      P[pbase + (size_t)(m*16 + kq*4 + j)*N + col] = acc[m][j];
}

// ---------- K1: Wh cvt + mask detect + GRU gate partial GEMMs ----------
__global__ __launch_bounds__(256) void k_pre(
    const float* __restrict__ wh, short* __restrict__ wh16,
    const unsigned int* __restrict__ mask, int mwords, int* __restrict__ flags,
    const float* __restrict__ x, const float* __restrict__ hprev,
    const float* __restrict__ w_ih, const float* __restrict__ w_hh,
    float* __restrict__ GI, float* __restrict__ GH)
{
  __shared__ __align__(16) short ls[2][64*64];
  int b = blockIdx.x, t = threadIdx.x;
  if (b < 256) {
    int i = b*256 + t;
    ((s16x8*)wh16)[i] = cvt8(wh + (size_t)i*8);
  } else if (b < 264) {
    __shared__ int f;
    if (t == 0) f = 0;
    __syncthreads();
    int loc = 0;
    for (int i = (b-256)*256 + t; i < mwords; i += 8*256) loc |= (mask[i] > 1u) ? 1 : 0;
    if (loc) atomicOr(&f, 1);
    __syncthreads();
    if (t == 0) flags[b-256] = f;
  } else {
    int gb = b - 264;              // 0..383
    int colI = gb % 24;
    int kseg = (gb / 24) % 8;
    int z    = gb / 192;
    mfma_small_body(z ? hprev : x, z ? w_hh : w_ih, z ? GH : GI,
                    512, 1536, colI*64, kseg, ls[0], ls[1], t);
  }
}

// ---------- GRU gate combine ----------
__global__ void gru_gate(const float* __restrict__ GI, const float* __restrict__ GH,
                         const float* __restrict__ b_ih, const float* __restrict__ b_hh,
                         const float* __restrict__ hprev, float* __restrict__ hid,
                         float* __restrict__ concat)
{
  int i = blockIdx.x*256 + threadIdx.x;
  int b = i >> 9, h = i & 511;
  float ir=0, iz=0, inn=0, hr=0, hz=0, hn=0;
  #pragma unroll
  for (int s = 0; s < 8; ++s) {
    const float* gi = GI + (size_t)s*(64*1536) + b*1536;
    const float* gh = GH + (size_t)s*(64*1536) + b*1536;
    ir += gi[h];      iz += gi[512+h];  inn += gi[1024+h];
    hr += gh[h];      hz += gh[512+h];  hn  += gh[1024+h];
  }
  ir += b_ih[h]; iz += b_ih[512+h]; inn += b_ih[1024+h];
  hr += b_hh[h]; hz += b_hh[512+h]; hn  += b_hh[1024+h];
  float r = sigm(ir + hr), z = sigm(iz + hz);
  float n = tanhfast(inn + r*hn);
  float hv = (1.f - z)*n + z*hprev[i];
  hid[i] = hv;
  concat[b*1536 + h] = hv;
}

// ---------- standalone small GEMM ----------
__global__ __launch_bounds__(256) void mfma_small(
    const float* __restrict__ A, const float* __restrict__ W,
    float* __restrict__ P, int K, int N)
{
  __shared__ __align__(16) short ls[2][64*64];
  mfma_small_body(A, W, P, K, N, blockIdx.x*64, blockIdx.y, ls[0], ls[1], threadIdx.x);
}

// ---------- combine K-split partials + up to two biases ----------
__global__ void combineN(const float* __restrict__ P, const float* __restrict__ b1,
                         const float* __restrict__ b2, float* __restrict__ dstv,
                         int N, int total, int nseg)
{
  int i = blockIdx.x*256 + threadIdx.x;
  if (i >= total) return;
  float a = 0.f;
  for (int s = 0; s < nseg; ++s) a += P[(size_t)s*total + i];
  int c = i % N;
  if (b1) a += b1[c];
  if (b2) a += b2[c];
  dstv[i] = a;
}

// ---------- score GEMM: BM=128 x BN=512 (full N) per block; A read ONCE ----------
// A f32 reg-staged (issue-early/write-late) -> bf16 LDS; B via gload_lds (L2-hot 1MB).
// Each block produces FINAL scores for its 128 rows (tanh-dot over all 512 cols).
__global__ __launch_bounds__(512) void score_gemm_bf16(
    const float* __restrict__ A, const __hip_bfloat16* __restrict__ Bw,
    const float* __restrict__ qv, const float* __restrict__ vb, float* __restrict__ dst)
{
  __shared__ __align__(16) short lsa[128*64];   // 16 KB
  __shared__ __align__(16) short lsb[512*64];   // 64 KB
  const int t = threadIdx.x;       // 0..511
  const int l = t & 63;
  const int w = t >> 6;            // 0..7
  const int wm = w >> 2;           // 0..1 : 64-row half
  const int wn = w & 3;            // 0..3 : 128-col quarter
  const int phys = blockIdx.x;     // 200 blocks (25 per XCD, bijective)
  const int logical = (phys & 7)*25 + (phys >> 3);
  const int mrow = logical * 128;

  f32x4 par[2][2];
  #define A_LOAD(k0)                                                              \
    _Pragma("unroll")                                                             \
    for (int q = 0; q < 2; ++q) {                                                 \
      int ci = q*512 + t; int r = ci >> 3, c = ci & 7;                            \
      const f32x4* ap = (const f32x4*)(A + (size_t)(mrow + r)*1024 + (k0) + c*8); \
      par[q][0] = ap[0]; par[q][1] = ap[1];                                       \
    }
  #define A_WRITE()                                                               \
    _Pragma("unroll")                                                             \
    for (int q = 0; q < 2; ++q) {                                                 \
      int ci = q*512 + t; int r = ci >> 3, c = ci & 7;                            \
      *(s16x8*)(lsa + r*64 + ((c ^ (r & 7)) << 3)) = cvt8v(par[q][0], par[q][1]); \
    }
  #define B_STAGE(k0)                                                             \
    _Pragma("unroll")                                                             \
    for (int i = 0; i < 8; ++i) {                                                 \
      int ci = i*512 + t; int r = ci >> 3, slot = ci & 7;                         \
      int c = slot ^ (r & 7);                                                     \
      gload16b(Bw + (size_t)r*1024 + (k0) + c*8, lsb + ci*8);                     \
    }

  f32x4 acc[4][8];
  #pragma unroll
  for (int m = 0; m < 4; ++m)
    #pragma unroll
    for (int n = 0; n < 8; ++n) { f32x4 z = {0.f,0.f,0.f,0.f}; acc[m][n] = z; }

  // prologue: stage tile 0
  A_LOAD(0)
  A_WRITE()
  B_STAGE(0)
  __syncthreads();

  for (int k = 0; k < 16; ++k) {
    if (k < 15) A_LOAD((k+1)*64)        // f32 loads in flight under MFMA
    #pragma unroll
    for (int kk = 0; kk < 64; kk += 32) {
      s16x8 bf[8];
      #pragma unroll
      for (int n = 0; n < 8; ++n) bf[n] = fragload16(lsb, wn*128 + n*16, kk, l);
      #pragma unroll
      for (int m = 0; m < 4; ++m) {
        s16x8 af = fragload16(lsa, wm*64 + m*16, kk, l);
        #pragma unroll
        for (int n = 0; n < 8; ++n)
          acc[m][n] = __builtin_amdgcn_mfma_f32_16x16x32_bf16(af, bf[n], acc[m][n], 0, 0, 0);
      }
    }
    __syncthreads();                     // all waves done reading tile k
    if (k < 15) { A_WRITE() B_STAGE((k+1)*64) }
    __syncthreads();                     // tile k+1 staged
  }
  #undef A_LOAD
  #undef A_WRITE
  #undef B_STAGE

  // epilogue: final score per row (reduce over all 512 cols)
  const int kq = l >> 4, lc = l & 15;
  float vv[8];
  #pragma unroll
  for (int n = 0; n < 8; ++n) vv[n] = vb[wn*128 + n*16 + lc];
  float* red = (float*)lsa;              // 128 rows x 4 col-waves
  #pragma unroll
  for (int m = 0; m < 4; ++m) {
    #pragma unroll
    for (int j = 0; j < 4; ++j) {
      int rl = wm*64 + m*16 + kq*4 + j;  // 0..127
      int r = mrow + rl;
      int b = r / SS;
      const float* qb = qv + b*HH + wn*128 + lc;
      float ps = 0.f;
      #pragma unroll
      for (int n = 0; n < 8; ++n) ps += vv[n]*tanhfast(acc[m][n][j] + qb[n*16]);
      #pragma unroll
      for (int o = 1; o < 16; o <<= 1) ps += __shfl_xor(ps, o);
      if (lc == 0) red[rl*4 + wn] = ps;
    }
  }
  __syncthreads();
  if (t < 128) {
    float s = red[t*4] + red[t*4+1] + red[t*4+2] + red[t*4+3];
    dst[mrow + t] = s;
  }
}

// ---------- vocab GEMM with register prefetch ----------
__global__ __launch_bounds__(256) void vocab_gemm(
    const float* __restrict__ OUTm, const float* __restrict__ Vhat,
    const float* __restrict__ Vb, float* __restrict__ logits,
    float* __restrict__ MAXP, float* __restrict__ SUMP)
{
  __shared__ __align__(16) short lsa[64*64];
  __shared__ __align__(16) short lsb[64*64];
  __shared__ float red[64][8];
  const int t = threadIdx.x, l = t & 63, w = t >> 6;
  const int vrow0 = blockIdx.x * 64;

  f32x4 acc[4];
  #pragma unroll
  for (int m = 0; m < 4; ++m) { f32x4 z = {0.f,0.f,0.f,0.f}; acc[m] = z; }

  f32x4 pa0[2][2], pb0[2][2], pa1[2][2], pb1[2][2];

  #define VLOAD(pa, pb, k0)                                                     \
    _Pragma("unroll")                                                           \
    for (int q = 0; q < 2; ++q) {                                               \
      int it = q*256 + t; int r = it >> 3, c = it & 7;                          \
      const f32x4* ap = (const f32x4*)(OUTm + (size_t)r*512 + (k0) + c*8);      \
      pa[q][0] = ap[0]; pa[q][1] = ap[1];                                       \
      const f32x4* bp = (const f32x4*)(Vhat + (size_t)(vrow0 + r)*512 + (k0) + c*8); \
      pb[q][0] = bp[0]; pb[q][1] = bp[1];                                       \
    }
  #define VSTEP(pa, pb)                                                         \
    _Pragma("unroll")                                                           \
    for (int q = 0; q < 2; ++q) {                                               \
      int it = q*256 + t; int r = it >> 3, c = it & 7;                          \
      int slot = (c ^ (r & 7)) << 3;                                            \
      *(s16x8*)(lsa + r*64 + slot) = cvt8v(pa[q][0], pa[q][1]);                 \
      *(s16x8*)(lsb + r*64 + slot) = cvt8v(pb[q][0], pb[q][1]);                 \
    }                                                                           \
    __syncthreads();                                                            \
    _Pragma("unroll")                                                           \
    for (int kk = 0; kk < 64; kk += 32) {                                       \
      s16x8 bf = fragload16(lsb, w*16, kk, l);                                  \
      _Pragma("unroll")                                                         \
      for (int m = 0; m < 4; ++m) {                                             \
        s16x8 af = fragload16(lsa, m*16, kk, l);                                \
        acc[m] = __builtin_amdgcn_mfma_f32_16x16x32_bf16(af, bf, acc[m], 0,0,0);\
      }                                                                         \
    }                                                                           \
    __syncthreads();

  VLOAD(pa0, pb0, 0)
  #pragma unroll
  for (int s2 = 0; s2 < 4; ++s2) {
    int k0 = s2*128;
    if (k0 + 64 < 512) { VLOAD(pa1, pb1, k0 + 64) }
    VSTEP(pa0, pb0)
    if (k0 + 128 < 512) { VLOAD(pa0, pb0, k0 + 128) }
    VSTEP(pa1, pb1)
  }
  #undef VLOAD
  #undef VSTEP

  const int kq = l >> 4, lc = l & 15;
  const int voc = vrow0 + w*16 + lc;
  const float bias = Vb[voc];
  #pragma unroll
  for (int m = 0; m < 4; ++m)
    #pragma unroll
    for (int j = 0; j < 4; ++j) {
      acc[m][j] += bias;
      logits[(size_t)(m*16 + kq*4 + j)*VVOC + voc] = acc[m][j];
    }
  #pragma unroll
  for (int m = 0; m < 4; ++m)
    #pragma unroll
    for (int j = 0; j < 4; ++j) {
      float v = acc[m][j];
      #pragma unroll
      for (int o = 1; o < 16; o <<= 1) v = fmaxf(v, __shfl_xor(v, o));
      if (lc == 0) red[m*16 + kq*4 + j][w] = v;
    }
  __syncthreads();
  float gmax[4][4];
  #pragma unroll
  for (int m = 0; m < 4; ++m)
    #pragma unroll
    for (int j = 0; j < 4; ++j) {
      int row = m*16 + kq*4 + j;
      gmax[m][j] = fmaxf(fmaxf(red[row][0], red[row][1]), fmaxf(red[row][2], red[row][3]));
    }
  __syncthreads();
  #pragma unroll
  for (int m = 0; m < 4; ++m)
    #pragma unroll
    for (int j = 0; j < 4; ++j) {
      float s = __expf(acc[m][j] - gmax[m][j]);
      #pragma unroll
      for (int o = 1; o < 16; o <<= 1) s += __shfl_xor(s, o);
      if (lc == 0) red[m*16 + kq*4 + j][4 + w] = s;
    }
  __syncthreads();
  if (t < 64) {
    float M = fmaxf(fmaxf(red[t][0], red[t][1]), fmaxf(red[t][2], red[t][3]));
    float S = red[t][4] + red[t][5] + red[t][6] + red[t][7];
    MAXP[blockIdx.x*64 + t] = M;
    SUMP[blockIdx.x*64 + t] = S;
  }
}

// ---------- vocab softmax normalize ----------
__global__ __launch_bounds__(256) void vnorm(
    const float* __restrict__ MAXP, const float* __restrict__ SUMP,
    float* __restrict__ logits)
{
  __shared__ float red[4];
  int b = blockIdx.x, q = blockIdx.y, t = threadIdx.x;
  float m = -INFINITY;
  for (int i = t; i < 500; i += 256) m = fmaxf(m, MAXP[i*64 + b]);
  m = blkmax(m, red, t);
  float z = 0.f;
  for (int i = t; i < 500; i += 256) z += SUMP[i*64 + b] * __expf(MAXP[i*64 + b] - m);
  z = blksum(z, red, t);
  float inv = 1.f / z;
  f32x4* p = (f32x4*)(logits + (size_t)b*VVOC + q*8000);
  for (int i = t; i < 2000; i += 256) {
    f32x4 v = p[i];
    #pragma unroll
    for (int c = 0; c < 4; ++c) v[c] = __expf(v[c] - m) * inv;
    p[i] = v;
  }
}

// ---------- masked softmax over S (reads final scores) ----------
__global__ void softmax_s(const float* __restrict__ score, const void* __restrict__ mask,
                          const int* __restrict__ flags, float* __restrict__ attn)
{
  __shared__ float red[4];
  int b = blockIdx.x, t = threadIdx.x;
  bool isbyte = (flags[0]|flags[1]|flags[2]|flags[3]|flags[4]|flags[5]|flags[6]|flags[7]) != 0;
  float sc0, sc1 = -INFINITY;
  {
    bool mv = isbyte ? (((const unsigned char*)mask)[b*SS + t] != 0)
                     : (((const int*)mask)[b*SS + t] != 0);
    sc0 = mv ? score[b*SS + t] : -INFINITY;
  }
  int s1 = t + 256;
  if (s1 < SS) {
    bool mv = isbyte ? (((const unsigned char*)mask)[b*SS + s1] != 0)
                     : (((const int*)mask)[b*SS + s1] != 0);
    sc1 = mv ? score[b*SS + s1] : -INFINITY;
  }
  float mx = blkmax(fmaxf(sc0, sc1), red, t);
  float e0 = __expf(sc0 - mx), e1 = __expf(sc1 - mx);
  float sum = blksum(e0 + e1, red, t);
  float inv = 1.f / sum;
  attn[b*SS + t] = e0 * inv;
  if (s1 < SS) attn[b*SS + s1] = e1 * inv;
}

// ---------- context partials from f32 enc: CTXP[sq][b][1024], 8 S-slices of 50 ----------
__global__ void ctx_part(const float* __restrict__ attn, const float* __restrict__ enc,
                         float* __restrict__ CTXP)
{
  int b = blockIdx.x, dh = blockIdx.y, sq = blockIdx.z;
  int d0 = dh*512 + threadIdx.x*2;
  const float* a = attn + b*SS + sq*50;
  const float* e = enc + (size_t)(b*SS + sq*50)*1024 + d0;
  float lo = 0.f, hi = 0.f;
  #pragma unroll 5
  for (int s = 0; s < 50; ++s) {
    f32x2 u = *(const f32x2*)(e + (size_t)s*1024);
    float av = a[s];
    lo += av * u[0];
    hi += av * u[1];
  }
  float* dst = CTXP + (size_t)sq*65536 + b*1024 + d0;
  dst[0] = lo; dst[1] = hi;
}

// ---------- ctx combine: ctx (d_out) + CONCAT[:,512:] ----------
__global__ void ctx_combine(const float* __restrict__ CTXP, float* __restrict__ ctx,
                            float* __restrict__ concat)
{
  int b = blockIdx.x;
  for (int d = threadIdx.x; d < 1024; d += 256) {
    float s = 0.f;
    #pragma unroll
    for (int q = 0; q < 8; ++q) s += CTXP[q*65536 + b*1024 + d];
    ctx[b*1024 + d] = s;
    concat[b*1536 + 512 + d] = s;
  }
}

// ---------- launch ----------
extern "C" void kernel_launch(void* const* d_in, const int* in_sizes, int n_in,
                              void* d_out, int out_size, void* d_ws, size_t ws_size,
                              hipStream_t stream) {
  (void)in_sizes; (void)n_in; (void)out_size; (void)ws_size;
  const float* x      = (const float*)d_in[0];
  const float* hprev  = (const float*)d_in[1];
  const float* enc    = (const float*)d_in[2];
  const void*  mask   = d_in[3];
  const float* w_ih   = (const float*)d_in[4];
  const float* w_hh   = (const float*)d_in[5];
  const float* b_ih   = (const float*)d_in[6];
  const float* b_hh   = (const float*)d_in[7];
  const float* Wh_w   = (const float*)d_in[8];
  const float* Wh_b   = (const float*)d_in[9];
  const float* Ws_w   = (const float*)d_in[10];
  const float* Ws_b   = (const float*)d_in[11];
  const float* vatt   = (const float*)d_in[12];
  const float* V_w    = (const float*)d_in[13];
  const float* V_b    = (const float*)d_in[14];
  const float* Vhat_w = (const float*)d_in[15];
  const float* Vhat_b = (const float*)d_in[16];

  float* out   = (float*)d_out;
  float* vocab = out;                    // [64,32000]
  float* attn  = out + 2048000;          // [64,400]
  float* ctx   = out + 2073600;          // [64,1024]
  float* hid   = out + 2139136;          // [64,512]

  float* WS     = (float*)d_ws;
  int*   FLAGS  = (int*)d_ws;            // 16 ints
  float* GI     = WS + 16;               // 8*64*1536 = 786432
  float* GH     = GI + 786432;           // 786432
  float* QP     = GH + 786432;           // 8*64*512 = 262144
  float* Q      = QP + 262144;           // 32768
  float* OUT    = Q + 32768;             // 32768
  float* SCORE  = OUT + 32768;           // 25600
  float* MAXP   = SCORE + 25600;         // 32000
  float* SUMP   = MAXP + 32000;          // 32000
  float* CTXP   = SUMP + 32000;          // 8*64*1024 = 524288
  float* OUTP   = CTXP + 524288;         // 24*64*512 = 786432
  float* CONCAT = OUTP + 786432;         // 64*1536 = 98304
  float* ENDF   = CONCAT + 98304;
  size_t f32_bytes = ((size_t)((char*)ENDF - (char*)d_ws) + 15) & ~(size_t)15;
  short* WH16  = (short*)((char*)d_ws + f32_bytes);   // 512*1024 bf16

  // 1. Wh cvt + mask detect + GRU gi/gh partials
  k_pre<<<dim3(648), 256, 0, stream>>>(Wh_w, WH16, (const unsigned int*)mask, 6400, FLAGS,
                                       x, hprev, w_ih, w_hh, GI, GH);
  // 2. GRU gate combine
  gru_gate<<<dim3(128), 256, 0, stream>>>(GI, GH, b_ih, b_hh, hprev, hid, CONCAT);
  // 3-4. q = hid@Ws^T + Ws_b + Wh_b
  mfma_small<<<dim3(8, 8), 256, 0, stream>>>(hid, Ws_w, QP, 512, 512);
  combineN<<<dim3(128), 256, 0, stream>>>(QP, Ws_b, Wh_b, Q, 512, 32768, 8);
  // 5. attention score GEMM: full-N blocks, A read once, final scores out
  score_gemm_bf16<<<dim3(200), 512, 0, stream>>>(
      enc, (const __hip_bfloat16*)WH16, Q, vatt, SCORE);
  // 6. masked softmax over S
  softmax_s<<<dim3(64), 256, 0, stream>>>(SCORE, mask, FLAGS, attn);
  // 7-8. context partials (f32 enc) + combine
  ctx_part<<<dim3(64, 2, 8), 256, 0, stream>>>(attn, enc, CTXP);
  ctx_combine<<<dim3(64), 256, 0, stream>>>(CTXP, ctx, CONCAT);
  // 9-10. out = CONCAT@V_w^T + V_b (K-split 24)
  mfma_small<<<dim3(8, 24), 256, 0, stream>>>(CONCAT, V_w, OUTP, 1536, 512);
  combineN<<<dim3(128), 256, 0, stream>>>(OUTP, V_b, nullptr, OUT, 512, 32768, 24);
  // 11. vocab GEMM + softmax partials
  vocab_gemm<<<dim3(500), 256, 0, stream>>>(OUT, Vhat_w, Vhat_b, vocab, MAXP, SUMP);
  // 12. softmax normalize
  vnorm<<<dim3(64, 4), 256, 0, stream>>>(MAXP, SUMP, vocab);
}

// Round 10
// 133.519 us; speedup vs baseline: 1.2028x; 1.0053x over previous
//
#include <hip/hip_runtime.h>
#include <hip/hip_bf16.h>
#include <stdint.h>

#define DI __device__ __forceinline__

using f32x2 = __attribute__((ext_vector_type(2))) float;
using f32x4 = __attribute__((ext_vector_type(4))) float;
using s16x8 = __attribute__((ext_vector_type(8))) short;

#define BB 64
#define SS 400
#define HH 512
#define VVOC 32000
#define MTOT (BB*SS)   // 25600

// ---------- helpers ----------
DI short bf16r(float f){
  __hip_bfloat16 h = __float2bfloat16(f);
  union { __hip_bfloat16 h; short s; } u; u.h = h; return u.s;
}
DI float sigm(float x){ return 1.f/(1.f + __expf(-x)); }
DI float tanhfast(float x){ x = fminf(x, 12.f); float e = __expf(2.f*x); return (e-1.f)/(e+1.f); }

DI void gload16b(const __hip_bfloat16* g, short* l){
  __builtin_amdgcn_global_load_lds(
      (const __attribute__((address_space(1))) __hip_bfloat16*)g,
      (__attribute__((address_space(3))) short*)l, 16, 0, 0);
}

DI float blkmax(float v, float* red, int t){
  #pragma unroll
  for (int o = 32; o; o >>= 1) v = fmaxf(v, __shfl_xor(v, o));
  if ((t & 63) == 0) red[t >> 6] = v;
  __syncthreads();
  v = fmaxf(fmaxf(red[0], red[1]), fmaxf(red[2], red[3]));
  __syncthreads();
  return v;
}
DI float blksum(float v, float* red, int t){
  #pragma unroll
  for (int o = 32; o; o >>= 1) v += __shfl_xor(v, o);
  if ((t & 63) == 0) red[t >> 6] = v;
  __syncthreads();
  v = red[0] + red[1] + red[2] + red[3];
  __syncthreads();
  return v;
}

DI s16x8 cvt8v(f32x4 a, f32x4 b){
  s16x8 o;
  o[0]=bf16r(a[0]); o[1]=bf16r(a[1]); o[2]=bf16r(a[2]); o[3]=bf16r(a[3]);
  o[4]=bf16r(b[0]); o[5]=bf16r(b[1]); o[6]=bf16r(b[2]); o[7]=bf16r(b[3]);
  return o;
}
DI s16x8 cvt8(const float* src){
  return cvt8v(((const f32x4*)src)[0], ((const f32x4*)src)[1]);
}

// bf16 LDS tile: row stride 64 shorts (128B), 8 chunks of 16B, slot = chunk ^ (row&7)
DI s16x8 fragload16(const short* tile, int rbase, int kk, int l){
  int r = rbase + (l & 15);
  int c = (kk >> 3) + (l >> 4);
  int slot = c ^ (r & 7);
  return *(const s16x8*)(tile + r*64 + slot*8);
}

// ---------- MFMA small GEMM body: P[kseg] = A[64,K](kseg) @ W[N,K]^T(kseg) ----------
DI void mfma_small_body(const float* __restrict__ A, const float* __restrict__ W,
                        float* __restrict__ P, int K, int N, int c0, int kseg,
                        short* lsa, short* lsb, int t)
{
  const int kbeg = kseg*64;
  const int l = t & 63, w = t >> 6;
  #pragma unroll
  for (int q = 0; q < 2; ++q) {
    int it = q*256 + t;
    int r = it >> 3, c = it & 7;
    int slot = (c ^ (r & 7)) << 3;
    *(s16x8*)(lsa + r*64 + slot) = cvt8(A + (size_t)r*K + kbeg + c*8);
    *(s16x8*)(lsb + r*64 + slot) = cvt8(W + (size_t)(c0 + r)*K + kbeg + c*8);
  }
  __syncthreads();
  f32x4 acc[4];
  #pragma unroll
  for (int m = 0; m < 4; ++m) { f32x4 z = {0.f,0.f,0.f,0.f}; acc[m] = z; }
  #pragma unroll
  for (int kk = 0; kk < 64; kk += 32) {
    s16x8 bf = fragload16(lsb, w*16, kk, l);
    #pragma unroll
    for (int m = 0; m < 4; ++m) {
      s16x8 af = fragload16(lsa, m*16, kk, l);
      acc[m] = __builtin_amdgcn_mfma_f32_16x16x32_bf16(af, bf, acc[m], 0, 0, 0);
    }
  }
  const int kq = l >> 4, lc = l & 15;
  const int col = c0 + w*16 + lc;
  size_t pbase = (size_t)kseg * 64 * N;
  #pragma unroll
  for (int m = 0; m < 4; ++m)
    #pragma unroll
    for (int j = 0; j < 4; ++j)
      P[pbase + (size_t)(m*16 + kq*4 + j)*N + col] = acc[m][j];
}

// ---------- K1: Wh cvt + mask detect + GRU gate partial GEMMs ----------
__global__ __launch_bounds__(256) void k_pre(
    const float* __restrict__ wh, short* __restrict__ wh16,
    const unsigned int* __restrict__ mask, int mwords, int* __restrict__ flags,
    const float* __restrict__ x, const float* __restrict__ hprev,
    const float* __restrict__ w_ih, const float* __restrict__ w_hh,
    float* __restrict__ GI, float* __restrict__ GH)
{
  __shared__ __align__(16) short ls[2][64*64];
  int b = blockIdx.x, t = threadIdx.x;
  if (b < 256) {
    int i = b*256 + t;
    ((s16x8*)wh16)[i] = cvt8(wh + (size_t)i*8);
  } else if (b < 264) {
    __shared__ int f;
    if (t == 0) f = 0;
    __syncthreads();
    int loc = 0;
    for (int i = (b-256)*256 + t; i < mwords; i += 8*256) loc |= (mask[i] > 1u) ? 1 : 0;
    if (loc) atomicOr(&f, 1);
    __syncthreads();
    if (t == 0) flags[b-256] = f;
  } else {
    int gb = b - 264;              // 0..383
    int colI = gb % 24;
    int kseg = (gb / 24) % 8;
    int z    = gb / 192;
    mfma_small_body(z ? hprev : x, z ? w_hh : w_ih, z ? GH : GI,
                    512, 1536, colI*64, kseg, ls[0], ls[1], t);
  }
}

// ---------- GRU gate combine ----------
__global__ void gru_gate(const float* __restrict__ GI, const float* __restrict__ GH,
                         const float* __restrict__ b_ih, const float* __restrict__ b_hh,
                         const float* __restrict__ hprev, float* __restrict__ hid,
                         float* __restrict__ concat)
{
  int i = blockIdx.x*256 + threadIdx.x;
  int b = i >> 9, h = i & 511;
  float ir=0, iz=0, inn=0, hr=0, hz=0, hn=0;
  #pragma unroll
  for (int s = 0; s < 8; ++s) {
    const float* gi = GI + (size_t)s*(64*1536) + b*1536;
    const float* gh = GH + (size_t)s*(64*1536) + b*1536;
    ir += gi[h];      iz += gi[512+h];  inn += gi[1024+h];
    hr += gh[h];      hz += gh[512+h];  hn  += gh[1024+h];
  }
  ir += b_ih[h]; iz += b_ih[512+h]; inn += b_ih[1024+h];
  hr += b_hh[h]; hz += b_hh[512+h]; hn  += b_hh[1024+h];
  float r = sigm(ir + hr), z = sigm(iz + hz);
  float n = tanhfast(inn + r*hn);
  float hv = (1.f - z)*n + z*hprev[i];
  hid[i] = hv;
  concat[b*1536 + h] = hv;
}

// ---------- standalone small GEMM ----------
__global__ __launch_bounds__(256) void mfma_small(
    const float* __restrict__ A, const float* __restrict__ W,
    float* __restrict__ P, int K, int N)
{
  __shared__ __align__(16) short ls[2][64*64];
  mfma_small_body(A, W, P, K, N, blockIdx.x*64, blockIdx.y, ls[0], ls[1], threadIdx.x);
}

// ---------- combine K-split partials + up to two biases ----------
__global__ void combineN(const float* __restrict__ P, const float* __restrict__ b1,
                         const float* __restrict__ b2, float* __restrict__ dstv,
                         int N, int total, int nseg)
{
  int i = blockIdx.x*256 + threadIdx.x;
  if (i >= total) return;
  float a = 0.f;
  for (int s = 0; s < nseg; ++s) a += P[(size_t)s*total + i];
  int c = i % N;
  if (b1) a += b1[c];
  if (b2) a += b2[c];
  dstv[i] = a;
}

// ---------- score GEMM: BM=128 x BN=512 (full N) per block; A read ONCE ----------
// __launch_bounds__(512, 2): min 2 waves/SIMD (1 block/CU) -> 256-VGPR cap, no acc spill.
__global__ __launch_bounds__(512, 2) void score_gemm_bf16(
    const float* __restrict__ A, const __hip_bfloat16* __restrict__ Bw,
    const float* __restrict__ qv, const float* __restrict__ vb, float* __restrict__ dst)
{
  __shared__ __align__(16) short lsa[128*64];   // 16 KB
  __shared__ __align__(16) short lsb[512*64];   // 64 KB
  const int t = threadIdx.x;       // 0..511
  const int l = t & 63;
  const int w = t >> 6;            // 0..7
  const int wm = w >> 2;           // 0..1 : 64-row half
  const int wn = w & 3;            // 0..3 : 128-col quarter
  const int phys = blockIdx.x;     // 200 blocks (25 per XCD, bijective)
  const int logical = (phys & 7)*25 + (phys >> 3);
  const int mrow = logical * 128;

  f32x4 par[2][2];
  #define A_LOAD(k0)                                                              \
    _Pragma("unroll")                                                             \
    for (int q = 0; q < 2; ++q) {                                                 \
      int ci = q*512 + t; int r = ci >> 3, c = ci & 7;                            \
      const f32x4* ap = (const f32x4*)(A + (size_t)(mrow + r)*1024 + (k0) + c*8); \
      par[q][0] = ap[0]; par[q][1] = ap[1];                                       \
    }
  #define A_WRITE()                                                               \
    _Pragma("unroll")                                                             \
    for (int q = 0; q < 2; ++q) {                                                 \
      int ci = q*512 + t; int r = ci >> 3, c = ci & 7;                            \
      *(s16x8*)(lsa + r*64 + ((c ^ (r & 7)) << 3)) = cvt8v(par[q][0], par[q][1]); \
    }
  #define B_STAGE(k0)                                                             \
    _Pragma("unroll")                                                             \
    for (int i = 0; i < 8; ++i) {                                                 \
      int ci = i*512 + t; int r = ci >> 3, slot = ci & 7;                         \
      int c = slot ^ (r & 7);                                                     \
      gload16b(Bw + (size_t)r*1024 + (k0) + c*8, lsb + ci*8);                     \
    }

  f32x4 acc[4][8];
  #pragma unroll
  for (int m = 0; m < 4; ++m)
    #pragma unroll
    for (int n = 0; n < 8; ++n) { f32x4 z = {0.f,0.f,0.f,0.f}; acc[m][n] = z; }

  // prologue: stage tile 0
  A_LOAD(0)
  A_WRITE()
  B_STAGE(0)
  __syncthreads();

  for (int k = 0; k < 16; ++k) {
    if (k < 15) A_LOAD((k+1)*64)        // f32 loads in flight under MFMA
    #pragma unroll
    for (int kk = 0; kk < 64; kk += 32) {
      s16x8 bf[8];
      #pragma unroll
      for (int n = 0; n < 8; ++n) bf[n] = fragload16(lsb, wn*128 + n*16, kk, l);
      #pragma unroll
      for (int m = 0; m < 4; ++m) {
        s16x8 af = fragload16(lsa, wm*64 + m*16, kk, l);
        #pragma unroll
        for (int n = 0; n < 8; ++n)
          acc[m][n] = __builtin_amdgcn_mfma_f32_16x16x32_bf16(af, bf[n], acc[m][n], 0, 0, 0);
      }
    }
    __syncthreads();                     // all waves done reading tile k
    if (k < 15) { A_WRITE() B_STAGE((k+1)*64) }
    __syncthreads();                     // tile k+1 staged
  }
  #undef A_LOAD
  #undef A_WRITE
  #undef B_STAGE

  // epilogue: final score per row (reduce over all 512 cols)
  const int kq = l >> 4, lc = l & 15;
  float vv[8];
  #pragma unroll
  for (int n = 0; n < 8; ++n) vv[n] = vb[wn*128 + n*16 + lc];
  float* red = (float*)lsa;              // 128 rows x 4 col-waves
  #pragma unroll
  for (int m = 0; m < 4; ++m) {
    #pragma unroll
    for (int j = 0; j < 4; ++j) {
      int rl = wm*64 + m*16 + kq*4 + j;  // 0..127
      int r = mrow + rl;
      int b = r / SS;
      const float* qb = qv + b*HH + wn*128 + lc;
      float ps = 0.f;
      #pragma unroll
      for (int n = 0; n < 8; ++n) ps += vv[n]*tanhfast(acc[m][n][j] + qb[n*16]);
      #pragma unroll
      for (int o = 1; o < 16; o <<= 1) ps += __shfl_xor(ps, o);
      if (lc == 0) red[rl*4 + wn] = ps;
    }
  }
  __syncthreads();
  if (t < 128) {
    float s = red[t*4] + red[t*4+1] + red[t*4+2] + red[t*4+3];
    dst[mrow + t] = s;
  }
}

// ---------- vocab GEMM with register prefetch ----------
__global__ __launch_bounds__(256) void vocab_gemm(
    const float* __restrict__ OUTm, const float* __restrict__ Vhat,
    const float* __restrict__ Vb, float* __restrict__ logits,
    float* __restrict__ MAXP, float* __restrict__ SUMP)
{
  __shared__ __align__(16) short lsa[64*64];
  __shared__ __align__(16) short lsb[64*64];
  __shared__ float red[64][8];
  const int t = threadIdx.x, l = t & 63, w = t >> 6;
  const int vrow0 = blockIdx.x * 64;

  f32x4 acc[4];
  #pragma unroll
  for (int m = 0; m < 4; ++m) { f32x4 z = {0.f,0.f,0.f,0.f}; acc[m] = z; }

  f32x4 pa0[2][2], pb0[2][2], pa1[2][2], pb1[2][2];

  #define VLOAD(pa, pb, k0)                                                     \
    _Pragma("unroll")                                                           \
    for (int q = 0; q < 2; ++q) {                                               \
      int it = q*256 + t; int r = it >> 3, c = it & 7;                          \
      const f32x4* ap = (const f32x4*)(OUTm + (size_t)r*512 + (k0) + c*8);      \
      pa[q][0] = ap[0]; pa[q][1] = ap[1];                                       \
      const f32x4* bp = (const f32x4*)(Vhat + (size_t)(vrow0 + r)*512 + (k0) + c*8); \
      pb[q][0] = bp[0]; pb[q][1] = bp[1];                                       \
    }
  #define VSTEP(pa, pb)                                                         \
    _Pragma("unroll")                                                           \
    for (int q = 0; q < 2; ++q) {                                               \
      int it = q*256 + t; int r = it >> 3, c = it & 7;                          \
      int slot = (c ^ (r & 7)) << 3;                                            \
      *(s16x8*)(lsa + r*64 + slot) = cvt8v(pa[q][0], pa[q][1]);                 \
      *(s16x8*)(lsb + r*64 + slot) = cvt8v(pb[q][0], pb[q][1]);                 \
    }                                                                           \
    __syncthreads();                                                            \
    _Pragma("unroll")                                                           \
    for (int kk = 0; kk < 64; kk += 32) {                                       \
      s16x8 bf = fragload16(lsb, w*16, kk, l);                                  \
      _Pragma("unroll")                                                         \
      for (int m = 0; m < 4; ++m) {                                             \
        s16x8 af = fragload16(lsa, m*16, kk, l);                                \
        acc[m] = __builtin_amdgcn_mfma_f32_16x16x32_bf16(af, bf, acc[m], 0,0,0);\
      }                                                                         \
    }                                                                           \
    __syncthreads();

  VLOAD(pa0, pb0, 0)
  #pragma unroll
  for (int s2 = 0; s2 < 4; ++s2) {
    int k0 = s2*128;
    if (k0 + 64 < 512) { VLOAD(pa1, pb1, k0 + 64) }
    VSTEP(pa0, pb0)
    if (k0 + 128 < 512) { VLOAD(pa0, pb0, k0 + 128) }
    VSTEP(pa1, pb1)
  }
  #undef VLOAD
  #undef VSTEP

  const int kq = l >> 4, lc = l & 15;
  const int voc = vrow0 + w*16 + lc;
  const float bias = Vb[voc];
  #pragma unroll
  for (int m = 0; m < 4; ++m)
    #pragma unroll
    for (int j = 0; j < 4; ++j) {
      acc[m][j] += bias;
      logits[(size_t)(m*16 + kq*4 + j)*VVOC + voc] = acc[m][j];
    }
  #pragma unroll
  for (int m = 0; m < 4; ++m)
    #pragma unroll
    for (int j = 0; j < 4; ++j) {
      float v = acc[m][j];
      #pragma unroll
      for (int o = 1; o < 16; o <<= 1) v = fmaxf(v, __shfl_xor(v, o));
      if (lc == 0) red[m*16 + kq*4 + j][w] = v;
    }
  __syncthreads();
  float gmax[4][4];
  #pragma unroll
  for (int m = 0; m < 4; ++m)
    #pragma unroll
    for (int j = 0; j < 4; ++j) {
      int row = m*16 + kq*4 + j;
      gmax[m][j] = fmaxf(fmaxf(red[row][0], red[row][1]), fmaxf(red[row][2], red[row][3]));
    }
  __syncthreads();
  #pragma unroll
  for (int m = 0; m < 4; ++m)
    #pragma unroll
    for (int j = 0; j < 4; ++j) {
      float s = __expf(acc[m][j] - gmax[m][j]);
      #pragma unroll
      for (int o = 1; o < 16; o <<= 1) s += __shfl_xor(s, o);
      if (lc == 0) red[m*16 + kq*4 + j][4 + w] = s;
    }
  __syncthreads();
  if (t < 64) {
    float M = fmaxf(fmaxf(red[t][0], red[t][1]), fmaxf(red[t][2], red[t][3]));
    float S = red[t][4] + red[t][5] + red[t][6] + red[t][7];
    MAXP[blockIdx.x*64 + t] = M;
    SUMP[blockIdx.x*64 + t] = S;
  }
}

// ---------- vocab softmax normalize ----------
__global__ __launch_bounds__(256) void vnorm(
    const float* __restrict__ MAXP, const float* __restrict__ SUMP,
    float* __restrict__ logits)
{
  __shared__ float red[4];
  int b = blockIdx.x, q = blockIdx.y, t = threadIdx.x;
  float m = -INFINITY;
  for (int i = t; i < 500; i += 256) m = fmaxf(m, MAXP[i*64 + b]);
  m = blkmax(m, red, t);
  float z = 0.f;
  for (int i = t; i < 500; i += 256) z += SUMP[i*64 + b] * __expf(MAXP[i*64 + b] - m);
  z = blksum(z, red, t);
  float inv = 1.f / z;
  f32x4* p = (f32x4*)(logits + (size_t)b*VVOC + q*8000);
  for (int i = t; i < 2000; i += 256) {
    f32x4 v = p[i];
    #pragma unroll
    for (int c = 0; c < 4; ++c) v[c] = __expf(v[c] - m) * inv;
    p[i] = v;
  }
}

// ---------- masked softmax over S (reads final scores) ----------
__global__ void softmax_s(const float* __restrict__ score, const void* __restrict__ mask,
                          const int* __restrict__ flags, float* __restrict__ attn)
{
  __shared__ float red[4];
  int b = blockIdx.x, t = threadIdx.x;
  bool isbyte = (flags[0]|flags[1]|flags[2]|flags[3]|flags[4]|flags[5]|flags[6]|flags[7]) != 0;
  float sc0, sc1 = -INFINITY;
  {
    bool mv = isbyte ? (((const unsigned char*)mask)[b*SS + t] != 0)
                     : (((const int*)mask)[b*SS + t] != 0);
    sc0 = mv ? score[b*SS + t] : -INFINITY;
  }
  int s1 = t + 256;
  if (s1 < SS) {
    bool mv = isbyte ? (((const unsigned char*)mask)[b*SS + s1] != 0)
                     : (((const int*)mask)[b*SS + s1] != 0);
    sc1 = mv ? score[b*SS + s1] : -INFINITY;
  }
  float mx = blkmax(fmaxf(sc0, sc1), red, t);
  float e0 = __expf(sc0 - mx), e1 = __expf(sc1 - mx);
  float sum = blksum(e0 + e1, red, t);
  float inv = 1.f / sum;
  attn[b*SS + t] = e0 * inv;
  if (s1 < SS) attn[b*SS + s1] = e1 * inv;
}

// ---------- context partials from f32 enc: CTXP[sq][b][1024], 8 S-slices of 50 ----------
__global__ void ctx_part(const float* __restrict__ attn, const float* __restrict__ enc,
                         float* __restrict__ CTXP)
{
  int b = blockIdx.x, dh = blockIdx.y, sq = blockIdx.z;
  int d0 = dh*512 + threadIdx.x*2;
  const float* a = attn + b*SS + sq*50;
  const float* e = enc + (size_t)(b*SS + sq*50)*1024 + d0;
  float lo = 0.f, hi = 0.f;
  #pragma unroll 5
  for (int s = 0; s < 50; ++s) {
    f32x2 u = *(const f32x2*)(e + (size_t)s*1024);
    float av = a[s];
    lo += av * u[0];
    hi += av * u[1];
  }
  float* dst = CTXP + (size_t)sq*65536 + b*1024 + d0;
  dst[0] = lo; dst[1] = hi;
}

// ---------- ctx combine: ctx (d_out) + CONCAT[:,512:] ----------
__global__ void ctx_combine(const float* __restrict__ CTXP, float* __restrict__ ctx,
                            float* __restrict__ concat)
{
  int b = blockIdx.x;
  for (int d = threadIdx.x; d < 1024; d += 256) {
    float s = 0.f;
    #pragma unroll
    for (int q = 0; q < 8; ++q) s += CTXP[q*65536 + b*1024 + d];
    ctx[b*1024 + d] = s;
    concat[b*1536 + 512 + d] = s;
  }
}

// ---------- launch ----------
extern "C" void kernel_launch(void* const* d_in, const int* in_sizes, int n_in,
                              void* d_out, int out_size, void* d_ws, size_t ws_size,
                              hipStream_t stream) {
  (void)in_sizes; (void)n_in; (void)out_size; (void)ws_size;
  const float* x      = (const float*)d_in[0];
  const float* hprev  = (const float*)d_in[1];
  const float* enc    = (const float*)d_in[2];
  const void*  mask   = d_in[3];
  const float* w_ih   = (const float*)d_in[4];
  const float* w_hh   = (const float*)d_in[5];
  const float* b_ih   = (const float*)d_in[6];
  const float* b_hh   = (const float*)d_in[7];
  const float* Wh_w   = (const float*)d_in[8];
  const float* Wh_b   = (const float*)d_in[9];
  const float* Ws_w   = (const float*)d_in[10];
  const float* Ws_b   = (const float*)d_in[11];
  const float* vatt   = (const float*)d_in[12];
  const float* V_w    = (const float*)d_in[13];
  const float* V_b    = (const float*)d_in[14];
  const float* Vhat_w = (const float*)d_in[15];
  const float* Vhat_b = (const float*)d_in[16];

  float* out   = (float*)d_out;
  float* vocab = out;                    // [64,32000]
  float* attn  = out + 2048000;          // [64,400]
  float* ctx   = out + 2073600;          // [64,1024]
  float* hid   = out + 2139136;          // [64,512]

  float* WS     = (float*)d_ws;
  int*   FLAGS  = (int*)d_ws;            // 16 ints
  float* GI     = WS + 16;               // 8*64*1536 = 786432
  float* GH     = GI + 786432;           // 786432
  float* QP     = GH + 786432;           // 8*64*512 = 262144
  float* Q      = QP + 262144;           // 32768
  float* OUT    = Q + 32768;             // 32768
  float* SCORE  = OUT + 32768;           // 25600
  float* MAXP   = SCORE + 25600;         // 32000
  float* SUMP   = MAXP + 32000;          // 32000
  float* CTXP   = SUMP + 32000;          // 8*64*1024 = 524288
  float* OUTP   = CTXP + 524288;         // 24*64*512 = 786432
  float* CONCAT = OUTP + 786432;         // 64*1536 = 98304
  float* ENDF   = CONCAT + 98304;
  size_t f32_bytes = ((size_t)((char*)ENDF - (char*)d_ws) + 15) & ~(size_t)15;
  short* WH16  = (short*)((char*)d_ws + f32_bytes);   // 512*1024 bf16

  // 1. Wh cvt + mask detect + GRU gi/gh partials
  k_pre<<<dim3(648), 256, 0, stream>>>(Wh_w, WH16, (const unsigned int*)mask, 6400, FLAGS,
                                       x, hprev, w_ih, w_hh, GI, GH);
  // 2. GRU gate combine
  gru_gate<<<dim3(128), 256, 0, stream>>>(GI, GH, b_ih, b_hh, hprev, hid, CONCAT);
  // 3-4. q = hid@Ws^T + Ws_b + Wh_b
  mfma_small<<<dim3(8, 8), 256, 0, stream>>>(hid, Ws_w, QP, 512, 512);
  combineN<<<dim3(128), 256, 0, stream>>>(QP, Ws_b, Wh_b, Q, 512, 32768, 8);
  // 5. attention score GEMM: full-N blocks, A read once, final scores out
  score_gemm_bf16<<<dim3(200), 512, 0, stream>>>(
      enc, (const __hip_bfloat16*)WH16, Q, vatt, SCORE);
  // 6. masked softmax over S
  softmax_s<<<dim3(64), 256, 0, stream>>>(SCORE, mask, FLAGS, attn);
  // 7-8. context partials (f32 enc) + combine
  ctx_part<<<dim3(64, 2, 8), 256, 0, stream>>>(attn, enc, CTXP);
  ctx_combine<<<dim3(64), 256, 0, stream>>>(CTXP, ctx, CONCAT);
  // 9-10. out = CONCAT@V_w^T + V_b (K-split 24)
  mfma_small<<<dim3(8, 24), 256, 0, stream>>>(CONCAT, V_w, OUTP, 1536, 512);
  combineN<<<dim3(128), 256, 0, stream>>>(OUTP, V_b, nullptr, OUT, 512, 32768, 24);
  // 11. vocab GEMM + softmax partials
  vocab_gemm<<<dim3(500), 256, 0, stream>>>(OUT, Vhat_w, Vhat_b, vocab, MAXP, SUMP);
  // 12. softmax normalize
  vnorm<<<dim3(64, 4), 256, 0, stream>>>(MAXP, SUMP, vocab);
}